// Round 7
// baseline (662.864 us; speedup 1.0000x reference)
//
#include <hip/hip_runtime.h>
#include <math.h>

// Problem constants: B=4, H=8, L=512, HD=64, D=512, RHO=0.1
// Workspace (floats):
//   Q   : 1M   [BH][512][64]   (QKV base; later reused as Of [B][L][512])
//   Kt  : 1M
//   V   : 1M
//   S   : 8M   [BH][512][512]  (scores -> later J -> softmax'd P)
//   Am  : 8M   (adjacency -> A_hat in place)
//   T   : 8M   (A_hat@S temp)
//   R   : 16K  (row inv-sqrt degrees)

typedef __attribute__((ext_vector_type(8))) short short8v;
typedef __attribute__((ext_vector_type(4))) float f32x4;

// ---------------------------------------------------------------------------
// bf16 split helper: pack 8 fp32 -> hi/lo bf16x8 (truncation split)
// ---------------------------------------------------------------------------
__device__ __forceinline__ void split8(const float* v, unsigned* hi, unsigned* lo)
{
    #pragma unroll
    for (int q = 0; q < 4; ++q) {
        const unsigned b0 = __float_as_uint(v[2 * q])     & 0xFFFF0000u;
        const unsigned b1 = __float_as_uint(v[2 * q + 1]) & 0xFFFF0000u;
        const float d0 = v[2 * q]     - __uint_as_float(b0);
        const float d1 = v[2 * q + 1] - __uint_as_float(b1);
        hi[q] = (b0 >> 16) | b1;
        lo[q] = (__float_as_uint(d0) >> 16) | (__float_as_uint(d1) & 0xFFFF0000u);
    }
}

// ---------------------------------------------------------------------------
// Split-bf16 MFMA GEMM. 128x128 tile, 256 threads (4 waves 2x2), K-step 32.
// BT=0: C = A @ B; BT=1: C = A @ B^T. acc = Ahi*Bhi + Ahi*Blo + Alo*Bhi.
// ---------------------------------------------------------------------------
template<int BT>
__global__ __launch_bounds__(256)
void gemm_mfma(const float* __restrict__ Ap, const float* __restrict__ Bp,
               float* __restrict__ Cp, int K, int lda, int ldb, int ldc,
               long sA, long sB, long sC, float scale)
{
    const float* __restrict__ A = Ap + (long)blockIdx.z * sA;
    const float* __restrict__ B = Bp + (long)blockIdx.z * sB;
    float* __restrict__ C = Cp + (long)blockIdx.z * sC;
    const int m0 = blockIdx.y << 7, n0 = blockIdx.x << 7;

    __shared__ short Ah[128 * 32], Al[128 * 32], Bh[128 * 32], Bl[128 * 32];

    const int tid = threadIdx.x;
    const int lane = tid & 63, wv = tid >> 6;
    const int wr = wv >> 1, wc = wv & 1;

    f32x4 acc[4][4] = {};

    for (int k0 = 0; k0 < K; k0 += 32) {
        {
            const int row = tid >> 1;
            const int swz = (row & 3) ^ ((row >> 2) & 3);
            #pragma unroll
            for (int gg = 0; gg < 2; ++gg) {
                const int g = ((tid & 1) << 1) + gg;
                const float* src = A + (long)(m0 + row) * lda + k0 + (g << 3);
                float v[8];
                *(float4*)&v[0] = *(const float4*)src;
                *(float4*)&v[4] = *(const float4*)(src + 4);
                unsigned hi[4], lo[4];
                split8(v, hi, lo);
                const int off = row * 32 + ((g ^ swz) << 3);
                *(uint4*)&Ah[off] = *(uint4*)hi;
                *(uint4*)&Al[off] = *(uint4*)lo;
            }
        }
        if (BT) {
            const int row = tid >> 1;
            const int swz = (row & 3) ^ ((row >> 2) & 3);
            #pragma unroll
            for (int gg = 0; gg < 2; ++gg) {
                const int g = ((tid & 1) << 1) + gg;
                const float* src = B + (long)(n0 + row) * ldb + k0 + (g << 3);
                float v[8];
                *(float4*)&v[0] = *(const float4*)src;
                *(float4*)&v[4] = *(const float4*)(src + 4);
                unsigned hi[4], lo[4];
                split8(v, hi, lo);
                const int off = row * 32 + ((g ^ swz) << 3);
                *(uint4*)&Bh[off] = *(uint4*)hi;
                *(uint4*)&Bl[off] = *(uint4*)lo;
            }
        } else {
            const int n = tid & 127;
            const int swz = (n & 3) ^ ((n >> 2) & 3);
            #pragma unroll
            for (int gg = 0; gg < 2; ++gg) {
                const int g = ((tid >> 7) << 1) + gg;
                float v[8];
                #pragma unroll
                for (int e = 0; e < 8; ++e)
                    v[e] = B[(long)(k0 + (g << 3) + e) * ldb + n0 + n];
                unsigned hi[4], lo[4];
                split8(v, hi, lo);
                const int off = n * 32 + ((g ^ swz) << 3);
                *(uint4*)&Bh[off] = *(uint4*)hi;
                *(uint4*)&Bl[off] = *(uint4*)lo;
            }
        }
        __syncthreads();

        {
            const int r = lane & 15, g = lane >> 4;
            const int lswz = (r & 3) ^ ((r >> 2) & 3);
            const int gslot = ((g ^ lswz) << 3);
            const int abase = ((wr << 6) + r) * 32 + gslot;
            const int bbase = ((wc << 6) + r) * 32 + gslot;
            short8v afh[4], afl[4], bfh[4], bfl[4];
            #pragma unroll
            for (int f = 0; f < 4; ++f) {
                afh[f] = *(short8v*)&Ah[abase + f * 512];
                afl[f] = *(short8v*)&Al[abase + f * 512];
                bfh[f] = *(short8v*)&Bh[bbase + f * 512];
                bfl[f] = *(short8v*)&Bl[bbase + f * 512];
            }
            #pragma unroll
            for (int fi = 0; fi < 4; ++fi)
                #pragma unroll
                for (int fj = 0; fj < 4; ++fj) {
                    acc[fi][fj] = __builtin_amdgcn_mfma_f32_16x16x32_bf16(
                        afh[fi], bfh[fj], acc[fi][fj], 0, 0, 0);
                    acc[fi][fj] = __builtin_amdgcn_mfma_f32_16x16x32_bf16(
                        afh[fi], bfl[fj], acc[fi][fj], 0, 0, 0);
                    acc[fi][fj] = __builtin_amdgcn_mfma_f32_16x16x32_bf16(
                        afl[fi], bfh[fj], acc[fi][fj], 0, 0, 0);
                }
        }
        __syncthreads();
    }

    // C/D layout: col = lane&15, row = (lane>>4)*4 + reg  [m89/m91]
    const int r = lane & 15, g = lane >> 4;
    #pragma unroll
    for (int fi = 0; fi < 4; ++fi) {
        const int gr0 = m0 + (wr << 6) + fi * 16 + g * 4;
        #pragma unroll
        for (int fj = 0; fj < 4; ++fj) {
            const int gc = n0 + (wc << 6) + fj * 16 + r;
            #pragma unroll
            for (int qq = 0; qq < 4; ++qq)
                C[(long)(gr0 + qq) * ldc + gc] = acc[fi][fj][qq] * scale;
        }
    }
}

// ---------------------------------------------------------------------------
// Fused QKV projection via split-bf16 MFMA: x[2048x512] @ {Wq|Wk|Wv}[512x512]
// -> QKV [3][BH][512][64]. Grid (12, 16).
// ---------------------------------------------------------------------------
__global__ __launch_bounds__(256)
void gemm_qkv_mfma(const float* __restrict__ x, const float* __restrict__ Wq,
                   const float* __restrict__ Wk, const float* __restrict__ Wv,
                   float* __restrict__ QKV)
{
    const int m0 = blockIdx.y << 7;
    const int ng = blockIdx.x << 7;
    const float* __restrict__ W = (ng < 512) ? Wq : (ng < 1024) ? Wk : Wv;
    const int n0 = ng & 511;
    float* __restrict__ C = QKV + (long)(ng >> 9) * (1 << 20);

    __shared__ short Ah[128 * 32], Al[128 * 32], Bh[128 * 32], Bl[128 * 32];

    const int tid = threadIdx.x;
    const int lane = tid & 63, wv = tid >> 6;
    const int wr = wv >> 1, wc = wv & 1;

    f32x4 acc[4][4] = {};

    for (int k0 = 0; k0 < 512; k0 += 32) {
        {
            const int row = tid >> 1;
            const int swz = (row & 3) ^ ((row >> 2) & 3);
            #pragma unroll
            for (int gg = 0; gg < 2; ++gg) {
                const int g = ((tid & 1) << 1) + gg;
                const float* src = x + (long)(m0 + row) * 512 + k0 + (g << 3);
                float v[8];
                *(float4*)&v[0] = *(const float4*)src;
                *(float4*)&v[4] = *(const float4*)(src + 4);
                unsigned hi[4], lo[4];
                split8(v, hi, lo);
                const int off = row * 32 + ((g ^ swz) << 3);
                *(uint4*)&Ah[off] = *(uint4*)hi;
                *(uint4*)&Al[off] = *(uint4*)lo;
            }
        }
        {
            const int n = tid & 127;
            const int swz = (n & 3) ^ ((n >> 2) & 3);
            #pragma unroll
            for (int gg = 0; gg < 2; ++gg) {
                const int g = ((tid >> 7) << 1) + gg;
                float v[8];
                #pragma unroll
                for (int e = 0; e < 8; ++e)
                    v[e] = W[(long)(k0 + (g << 3) + e) * 512 + n0 + n];
                unsigned hi[4], lo[4];
                split8(v, hi, lo);
                const int off = n * 32 + ((g ^ swz) << 3);
                *(uint4*)&Bh[off] = *(uint4*)hi;
                *(uint4*)&Bl[off] = *(uint4*)lo;
            }
        }
        __syncthreads();

        {
            const int r = lane & 15, g = lane >> 4;
            const int lswz = (r & 3) ^ ((r >> 2) & 3);
            const int gslot = ((g ^ lswz) << 3);
            const int abase = ((wr << 6) + r) * 32 + gslot;
            const int bbase = ((wc << 6) + r) * 32 + gslot;
            short8v afh[4], afl[4], bfh[4], bfl[4];
            #pragma unroll
            for (int f = 0; f < 4; ++f) {
                afh[f] = *(short8v*)&Ah[abase + f * 512];
                afl[f] = *(short8v*)&Al[abase + f * 512];
                bfh[f] = *(short8v*)&Bh[bbase + f * 512];
                bfl[f] = *(short8v*)&Bl[bbase + f * 512];
            }
            #pragma unroll
            for (int fi = 0; fi < 4; ++fi)
                #pragma unroll
                for (int fj = 0; fj < 4; ++fj) {
                    acc[fi][fj] = __builtin_amdgcn_mfma_f32_16x16x32_bf16(
                        afh[fi], bfh[fj], acc[fi][fj], 0, 0, 0);
                    acc[fi][fj] = __builtin_amdgcn_mfma_f32_16x16x32_bf16(
                        afh[fi], bfl[fj], acc[fi][fj], 0, 0, 0);
                    acc[fi][fj] = __builtin_amdgcn_mfma_f32_16x16x32_bf16(
                        afl[fi], bfh[fj], acc[fi][fj], 0, 0, 0);
                }
        }
        __syncthreads();
    }

    const int r = lane & 15, g = lane >> 4;
    #pragma unroll
    for (int fi = 0; fi < 4; ++fi) {
        const int gr0 = m0 + (wr << 6) + fi * 16 + g * 4;
        #pragma unroll
        for (int fj = 0; fj < 4; ++fj) {
            const int nl = n0 + (wc << 6) + fj * 16 + r;
            const int h = nl >> 6, d = nl & 63;
            #pragma unroll
            for (int qq = 0; qq < 4; ++qq) {
                const int m = gr0 + qq;
                const int b = m >> 9, l = m & 511;
                C[((long)((b * 8 + h) * 512 + l)) * 64 + d] = acc[fi][fj][qq];
            }
        }
    }
}

// ---------------------------------------------------------------------------
// Adjacency v6: A[i,k] = 2^-15 * sum_j (p = S_ij*S_kj) if p > 0.1*64, diag 0.
// (pow2 prescale commutes with fp rounding -> decisions match reference.)
// 64x64 tile, upper-tri tile pairs (36), mirrored write. 4 waves/block.
// SHARED double-buffered staging: 256 threads stage one 16-j chunk (8 floats
// each); wave wv computes j's {4wv..4wv+3} of each chunk into private
// acc[8][8]. One barrier/chunk; next chunk's global loads issue before
// compute, ds_writes after (vmcnt hides under 1024 VALU ops).
// launch_bounds(256,4) pins VGPR<=128 (the R6 cliff). In-LDS quarter-wise
// tree reduce combines the 4 wave partials; wave 0 finalizes + mirrors.
// ---------------------------------------------------------------------------
__global__ __launch_bounds__(256, 4)
void adj_kernel(const float* __restrict__ S, float* __restrict__ A)
{
    const int bh = blockIdx.y;
    const float* __restrict__ Sh = S + (long)bh * 262144;
    float* __restrict__ Ah = A + (long)bh * 262144;

    int ti = 0, rem = blockIdx.x;
    while (rem >= 8 - ti) { rem -= 8 - ti; ++ti; }
    const int tk = ti + rem;
    const int i0 = ti << 6, k0 = tk << 6;

    __shared__ float smem[4352];        // 2 buffers x (L[16][68] + R[16][68])

    const int tid  = threadIdx.x;
    const int lane = tid & 63;
    const int wv   = tid >> 6;
    const int ly8  = (lane >> 3) << 3;
    const int lx8  = (lane & 7) << 3;
    const int row  = tid >> 2;           // staging row 0..63
    const int q    = tid & 3;            // staging j-quad

    const float RHO64 = 6.4f;            // 0.1f * 64, exact in fp32

    float acc[8][8] = {};

    const float* srcL = Sh + (long)(i0 + row) * 512 + (q << 2);
    const float* srcR = Sh + (long)(k0 + row) * 512 + (q << 2);

    // stage chunk 0 into buffer 0
    {
        const float4 rl = *(const float4*)srcL;
        const float4 rr = *(const float4*)srcR;
        float* dL = &smem[0];
        float* dR = &smem[1088];
        dL[((q << 2) + 0) * 68 + row] = rl.x;
        dL[((q << 2) + 1) * 68 + row] = rl.y;
        dL[((q << 2) + 2) * 68 + row] = rl.z;
        dL[((q << 2) + 3) * 68 + row] = rl.w;
        dR[((q << 2) + 0) * 68 + row] = rr.x;
        dR[((q << 2) + 1) * 68 + row] = rr.y;
        dR[((q << 2) + 2) * 68 + row] = rr.z;
        dR[((q << 2) + 3) * 68 + row] = rr.w;
    }
    __syncthreads();

    for (int c = 0; c < 32; ++c) {
        float4 rl, rr;
        if (c < 31) {                    // issue next chunk's loads FIRST
            rl = *(const float4*)(srcL + ((c + 1) << 4));
            rr = *(const float4*)(srcR + ((c + 1) << 4));
        }
        // compute current chunk: this wave's 4 j's
        {
            const float* sL = &smem[(c & 1) * 2176];
            const float* sR = &smem[(c & 1) * 2176 + 1088];
            #pragma unroll
            for (int jj = 0; jj < 4; ++jj) {
                const int jrow = (wv << 2) + jj;
                float a[8], b[8];
                *(float4*)&a[0] = *(const float4*)&sL[jrow * 68 + ly8];
                *(float4*)&a[4] = *(const float4*)&sL[jrow * 68 + ly8 + 4];
                *(float4*)&b[0] = *(const float4*)&sR[jrow * 68 + lx8];
                *(float4*)&b[4] = *(const float4*)&sR[jrow * 68 + lx8 + 4];
                #pragma unroll
                for (int i = 0; i < 8; ++i)
                    #pragma unroll
                    for (int j = 0; j < 8; ++j) {
                        const float u = a[i] * b[j];
                        if (u > RHO64) acc[i][j] += u;
                    }
            }
        }
        // stage next chunk into the other buffer (vmcnt hidden by compute)
        if (c < 31) {
            float* dL = &smem[((c + 1) & 1) * 2176];
            float* dR = &smem[((c + 1) & 1) * 2176 + 1088];
            dL[((q << 2) + 0) * 68 + row] = rl.x;
            dL[((q << 2) + 1) * 68 + row] = rl.y;
            dL[((q << 2) + 2) * 68 + row] = rl.z;
            dL[((q << 2) + 3) * 68 + row] = rl.w;
            dR[((q << 2) + 0) * 68 + row] = rr.x;
            dR[((q << 2) + 1) * 68 + row] = rr.y;
            dR[((q << 2) + 2) * 68 + row] = rr.z;
            dR[((q << 2) + 3) * 68 + row] = rr.w;
        }
        __syncthreads();
    }

    // ---- reduce wave partials in quarters (16 floats), stride-17 buffers ----
    float* buf0 = &smem[0];
    float* buf1 = &smem[1088];

    #pragma unroll
    for (int qp = 0; qp < 4; ++qp) {
        __syncthreads();
        if (wv == 1 || wv == 2) {
            float* dst = (wv == 1 ? buf0 : buf1) + lane * 17;
            #pragma unroll
            for (int e = 0; e < 16; ++e)
                dst[e] = acc[(qp << 1) + (e >> 3)][e & 7];
        }
        __syncthreads();
        if (wv == 0 || wv == 3) {
            const float* src = (wv == 0 ? buf0 : buf1) + lane * 17;
            #pragma unroll
            for (int e = 0; e < 16; ++e)
                acc[(qp << 1) + (e >> 3)][e & 7] += src[e];
        }
    }
    #pragma unroll
    for (int qp = 0; qp < 4; ++qp) {
        __syncthreads();
        if (wv == 3) {
            float* dst = buf0 + lane * 17;
            #pragma unroll
            for (int e = 0; e < 16; ++e)
                dst[e] = acc[(qp << 1) + (e >> 3)][e & 7];
        }
        __syncthreads();
        if (wv == 0) {
            const float* src = buf0 + lane * 17;
            #pragma unroll
            for (int e = 0; e < 16; ++e)
                acc[(qp << 1) + (e >> 3)][e & 7] += src[e];
        }
    }

    if (wv == 0) {
        const float SC = 1.0f / 32768.0f;    // 2^-15 = (1/64)*(1/512), exact
        float f[8][8];
        #pragma unroll
        for (int i = 0; i < 8; ++i)
            #pragma unroll
            for (int j = 0; j < 8; ++j)
                f[i][j] = acc[i][j] * SC;
        if (ti == tk) {
            #pragma unroll
            for (int i = 0; i < 8; ++i)
                #pragma unroll
                for (int j = 0; j < 8; ++j)
                    if (ly8 + i == lx8 + j) f[i][j] = 0.0f;
        }
        #pragma unroll
        for (int i = 0; i < 8; ++i) {
            float* dst = Ah + (long)(i0 + ly8 + i) * 512 + k0 + lx8;
            *(float4*)dst       = make_float4(f[i][0], f[i][1], f[i][2], f[i][3]);
            *(float4*)(dst + 4) = make_float4(f[i][4], f[i][5], f[i][6], f[i][7]);
        }
        if (ti != tk) {
            #pragma unroll
            for (int j = 0; j < 8; ++j) {
                float* dst = Ah + (long)(k0 + lx8 + j) * 512 + i0 + ly8;
                *(float4*)dst       = make_float4(f[0][j], f[1][j], f[2][j], f[3][j]);
                *(float4*)(dst + 4) = make_float4(f[4][j], f[5][j], f[6][j], f[7][j]);
            }
        }
    }
}

// ---------------------------------------------------------------------------
// Row degree: R[row] = 1/sqrt(clip(1 + sum_k A[row,k], 1e-6))
// ---------------------------------------------------------------------------
__global__ __launch_bounds__(256)
void rowsum_kernel(const float* __restrict__ A, float* __restrict__ R)
{
    const int row = (blockIdx.x << 2) + (threadIdx.x >> 6);
    const int lane = threadIdx.x & 63;
    const float* p = A + (long)row * 512;
    float s = 0.0f;
    #pragma unroll
    for (int t = 0; t < 8; ++t) s += p[lane + (t << 6)];
    #pragma unroll
    for (int off = 32; off; off >>= 1) s += __shfl_xor(s, off, 64);
    if (lane == 0) R[row] = 1.0f / sqrtf(fmaxf(1.0f + s, 1e-6f));
}

// ---------------------------------------------------------------------------
// A_hat[i,k] = R[i]*R[k]*(A[i,k] + (i==k)) in place
// ---------------------------------------------------------------------------
__global__ __launch_bounds__(256)
void ahat_kernel(float* __restrict__ A, const float* __restrict__ R)
{
    const long i4 = ((long)blockIdx.x * 256 + threadIdx.x) << 2;
    const long off = i4 & 262143;
    const long bh = i4 >> 18;
    const int i = (int)(off >> 9);
    const int k = (int)(off & 511);
    const float ri = R[(bh << 9) + i];
    const float* Rk = R + (bh << 9) + k;
    float4 v = *(float4*)(A + i4);
    v.x = ri * Rk[0] * (v.x + ((k + 0) == i ? 1.0f : 0.0f));
    v.y = ri * Rk[1] * (v.y + ((k + 1) == i ? 1.0f : 0.0f));
    v.z = ri * Rk[2] * (v.z + ((k + 2) == i ? 1.0f : 0.0f));
    v.w = ri * Rk[3] * (v.w + ((k + 3) == i ? 1.0f : 0.0f));
    *(float4*)(A + i4) = v;
}

// ---------------------------------------------------------------------------
// Row softmax over 512, in place. Wave per row, 4 rows/block, no barriers.
// ---------------------------------------------------------------------------
__global__ __launch_bounds__(256)
void softmax_kernel(float* __restrict__ P)
{
    const int row = (blockIdx.x << 2) + (threadIdx.x >> 6);
    const int lane = threadIdx.x & 63;
    float* p = P + (long)row * 512 + (lane << 3);
    float4 v0 = *(float4*)p;
    float4 v1 = *(float4*)(p + 4);
    float mx = fmaxf(fmaxf(fmaxf(v0.x, v0.y), fmaxf(v0.z, v0.w)),
                     fmaxf(fmaxf(v1.x, v1.y), fmaxf(v1.z, v1.w)));
    #pragma unroll
    for (int off = 32; off; off >>= 1) mx = fmaxf(mx, __shfl_xor(mx, off, 64));
    float e[8];
    e[0] = __expf(v0.x - mx); e[1] = __expf(v0.y - mx);
    e[2] = __expf(v0.z - mx); e[3] = __expf(v0.w - mx);
    e[4] = __expf(v1.x - mx); e[5] = __expf(v1.y - mx);
    e[6] = __expf(v1.z - mx); e[7] = __expf(v1.w - mx);
    float s = (((e[0] + e[1]) + (e[2] + e[3])) + ((e[4] + e[5]) + (e[6] + e[7])));
    #pragma unroll
    for (int off = 32; off; off >>= 1) s += __shfl_xor(s, off, 64);
    const float inv = 1.0f / s;
    *(float4*)p       = make_float4(e[0] * inv, e[1] * inv, e[2] * inv, e[3] * inv);
    *(float4*)(p + 4) = make_float4(e[4] * inv, e[5] * inv, e[6] * inv, e[7] * inv);
}

// ---------------------------------------------------------------------------
// O = P @ V per head via split-bf16 MFMA, writing DIRECTLY to Of layout
// [B][L][H*HD]. M=512, N=64, K=512. 128x64 tile, 4 waves stacked on M.
// Grid (1, 4, 32).
// ---------------------------------------------------------------------------
__global__ __launch_bounds__(256)
void gemm_pv_mfma(const float* __restrict__ P, const float* __restrict__ V,
                  float* __restrict__ Of)
{
    const int bh = blockIdx.z;
    const float* __restrict__ Pp = P + (long)bh * 262144;
    const float* __restrict__ Vp = V + (long)bh * 32768;
    const int bb = bh >> 3, hh = bh & 7;
    const int m0 = blockIdx.y << 7;

    __shared__ short Ph[128 * 32], Pl[128 * 32], Vh[64 * 32], Vl[64 * 32];

    const int tid = threadIdx.x;
    const int lane = tid & 63, wv = tid >> 6;

    f32x4 acc[2][4] = {};

    for (int k0 = 0; k0 < 512; k0 += 32) {
        {
            const int row = tid >> 1;
            const int swz = (row & 3) ^ ((row >> 2) & 3);
            #pragma unroll
            for (int gg = 0; gg < 2; ++gg) {
                const int g = ((tid & 1) << 1) + gg;
                const float* src = Pp + (long)(m0 + row) * 512 + k0 + (g << 3);
                float v[8];
                *(float4*)&v[0] = *(const float4*)src;
                *(float4*)&v[4] = *(const float4*)(src + 4);
                unsigned hi[4], lo[4];
                split8(v, hi, lo);
                const int off = row * 32 + ((g ^ swz) << 3);
                *(uint4*)&Ph[off] = *(uint4*)hi;
                *(uint4*)&Pl[off] = *(uint4*)lo;
            }
        }
        {
            const int n = tid & 63, g = tid >> 6;
            const int swz = (n & 3) ^ ((n >> 2) & 3);
            float v[8];
            #pragma unroll
            for (int e = 0; e < 8; ++e)
                v[e] = Vp[(long)(k0 + (g << 3) + e) * 64 + n];
            unsigned hi[4], lo[4];
            split8(v, hi, lo);
            const int off = n * 32 + ((g ^ swz) << 3);
            *(uint4*)&Vh[off] = *(uint4*)hi;
            *(uint4*)&Vl[off] = *(uint4*)lo;
        }
        __syncthreads();

        {
            const int r = lane & 15, g = lane >> 4;
            const int lswz = (r & 3) ^ ((r >> 2) & 3);
            const int gslot = ((g ^ lswz) << 3);
            short8v afh[2], afl[2], bfh[4], bfl[4];
            #pragma unroll
            for (int fi = 0; fi < 2; ++fi) {
                const int abase = ((wv << 5) + (fi << 4) + r) * 32 + gslot;
                afh[fi] = *(short8v*)&Ph[abase];
                afl[fi] = *(short8v*)&Pl[abase];
            }
            #pragma unroll
            for (int fj = 0; fj < 4; ++fj) {
                const int bbase = ((fj << 4) + r) * 32 + gslot;
                bfh[fj] = *(short8v*)&Vh[bbase];
                bfl[fj] = *(short8v*)&Vl[bbase];
            }
            #pragma unroll
            for (int fi = 0; fi < 2; ++fi)
                #pragma unroll
                for (int fj = 0; fj < 4; ++fj) {
                    acc[fi][fj] = __builtin_amdgcn_mfma_f32_16x16x32_bf16(
                        afh[fi], bfh[fj], acc[fi][fj], 0, 0, 0);
                    acc[fi][fj] = __builtin_amdgcn_mfma_f32_16x16x32_bf16(
                        afh[fi], bfl[fj], acc[fi][fj], 0, 0, 0);
                    acc[fi][fj] = __builtin_amdgcn_mfma_f32_16x16x32_bf16(
                        afl[fi], bfh[fj], acc[fi][fj], 0, 0, 0);
                }
        }
        __syncthreads();
    }

    const int r = lane & 15, g = lane >> 4;
    #pragma unroll
    for (int fi = 0; fi < 2; ++fi) {
        const int l0 = m0 + (wv << 5) + fi * 16 + g * 4;
        #pragma unroll
        for (int fj = 0; fj < 4; ++fj) {
            const int d = fj * 16 + r;
            #pragma unroll
            for (int qq = 0; qq < 4; ++qq)
                Of[((long)((bb << 9) + l0 + qq) << 9) + (hh << 6) + d] = acc[fi][fj][qq];
        }
    }
}

// ---------------------------------------------------------------------------
extern "C" void kernel_launch(void* const* d_in, const int* in_sizes, int n_in,
                              void* d_out, int out_size, void* d_ws, size_t ws_size,
                              hipStream_t stream)
{
    const float* x  = (const float*)d_in[0];
    const float* Wq = (const float*)d_in[1];
    const float* Wk = (const float*)d_in[2];
    const float* Wv = (const float*)d_in[3];
    const float* Wo = (const float*)d_in[4];
    float* out = (float*)d_out;

    float* ws = (float*)d_ws;
    float* Q  = ws;                       // 1M floats (QKV base; later Of)
    float* Kt = Q  + (1u << 20);          // 1M
    float* V  = Kt + (1u << 20);          // 1M
    float* S  = V  + (1u << 20);          // 8M
    float* Am = S  + (8u << 20);          // 8M (adjacency -> A_hat)
    float* T  = Am + (8u << 20);          // 8M (A_hat@S temp)
    float* R  = T  + (8u << 20);          // 16K

    dim3 blk(256);

    // 1) fused QKV projections (split-bf16 MFMA)
    gemm_qkv_mfma<<<dim3(12, 16, 1), blk, 0, stream>>>(x, Wq, Wk, Wv, Q);

    // 2) S = Q K^T per head (MFMA, K=64)
    gemm_mfma<1><<<dim3(4, 4, 32), blk, 0, stream>>>(Q, Kt, S, 64, 64, 64, 512,
                                                     32768, 32768, 262144, 1.0f);

    // 3) adjacency (shared dbuf staging, 4-way j-split, mirrored write)
    adj_kernel<<<dim3(36, 32), blk, 0, stream>>>(S, Am);

    // 4) row degrees -> R
    rowsum_kernel<<<dim3(4096), blk, 0, stream>>>(Am, R);

    // 5) A_hat in place
    ahat_kernel<<<dim3(8192), blk, 0, stream>>>(Am, R);

    // 6) T = A_hat @ S (MFMA)
    gemm_mfma<0><<<dim3(4, 4, 32), blk, 0, stream>>>(Am, S, T, 512, 512, 512, 512,
                                                     262144, 262144, 262144, 1.0f);

    // 7) J = T @ A_hat^T / 8 -> S (MFMA)
    gemm_mfma<1><<<dim3(4, 4, 32), blk, 0, stream>>>(T, Am, S, 512, 512, 512, 512,
                                                     262144, 262144, 262144, 0.125f);

    // 8) softmax rows of J (wave per row)
    softmax_kernel<<<dim3(4096), blk, 0, stream>>>(S);

    // 9) O = P @ V -> Of directly (reuse Q buffer)
    gemm_pv_mfma<<<dim3(1, 4, 32), blk, 0, stream>>>(S, V, Q);

    // 10) out = Of @ Wo (MFMA)
    gemm_mfma<0><<<dim3(4, 16, 1), blk, 0, stream>>>(Q, Wo, out, 512, 512, 512, 512,
                                                     0, 0, 0, 1.0f);
}

// Round 8
// 536.841 us; speedup vs baseline: 1.2347x; 1.2347x over previous
//
#include <hip/hip_runtime.h>
#include <math.h>

// Problem constants: B=4, H=8, L=512, HD=64, D=512, RHO=0.1
// Workspace (floats):
//   Q   : 1M   [BH][512][64]   (QKV base; later reused as Of [B][L][512])
//   Kt  : 1M
//   V   : 1M
//   S   : 8M   [BH][512][512]  (scores -> later J -> softmax'd P)
//   Am  : 8M   (adjacency -> A_hat in place)
//   T   : 8M   (A_hat@S temp)
//   R   : 16K  (row inv-sqrt degrees)

typedef __attribute__((ext_vector_type(8))) short short8v;
typedef __attribute__((ext_vector_type(4))) float f32x4;

// ---------------------------------------------------------------------------
// bf16 split helper: pack 8 fp32 -> hi/lo bf16x8 (truncation split)
// ---------------------------------------------------------------------------
__device__ __forceinline__ void split8(const float* v, unsigned* hi, unsigned* lo)
{
    #pragma unroll
    for (int q = 0; q < 4; ++q) {
        const unsigned b0 = __float_as_uint(v[2 * q])     & 0xFFFF0000u;
        const unsigned b1 = __float_as_uint(v[2 * q + 1]) & 0xFFFF0000u;
        const float d0 = v[2 * q]     - __uint_as_float(b0);
        const float d1 = v[2 * q + 1] - __uint_as_float(b1);
        hi[q] = (b0 >> 16) | b1;
        lo[q] = (__float_as_uint(d0) >> 16) | (__float_as_uint(d1) & 0xFFFF0000u);
    }
}

// ---------------------------------------------------------------------------
// Split-bf16 MFMA GEMM. 128x128 tile, 256 threads (4 waves 2x2), K-step 32.
// BT=0: C = A @ B; BT=1: C = A @ B^T. acc = Ahi*Bhi + Ahi*Blo + Alo*Bhi.
// ---------------------------------------------------------------------------
template<int BT>
__global__ __launch_bounds__(256)
void gemm_mfma(const float* __restrict__ Ap, const float* __restrict__ Bp,
               float* __restrict__ Cp, int K, int lda, int ldb, int ldc,
               long sA, long sB, long sC, float scale)
{
    const float* __restrict__ A = Ap + (long)blockIdx.z * sA;
    const float* __restrict__ B = Bp + (long)blockIdx.z * sB;
    float* __restrict__ C = Cp + (long)blockIdx.z * sC;
    const int m0 = blockIdx.y << 7, n0 = blockIdx.x << 7;

    __shared__ short Ah[128 * 32], Al[128 * 32], Bh[128 * 32], Bl[128 * 32];

    const int tid = threadIdx.x;
    const int lane = tid & 63, wv = tid >> 6;
    const int wr = wv >> 1, wc = wv & 1;

    f32x4 acc[4][4] = {};

    for (int k0 = 0; k0 < K; k0 += 32) {
        {
            const int row = tid >> 1;
            const int swz = (row & 3) ^ ((row >> 2) & 3);
            #pragma unroll
            for (int gg = 0; gg < 2; ++gg) {
                const int g = ((tid & 1) << 1) + gg;
                const float* src = A + (long)(m0 + row) * lda + k0 + (g << 3);
                float v[8];
                *(float4*)&v[0] = *(const float4*)src;
                *(float4*)&v[4] = *(const float4*)(src + 4);
                unsigned hi[4], lo[4];
                split8(v, hi, lo);
                const int off = row * 32 + ((g ^ swz) << 3);
                *(uint4*)&Ah[off] = *(uint4*)hi;
                *(uint4*)&Al[off] = *(uint4*)lo;
            }
        }
        if (BT) {
            const int row = tid >> 1;
            const int swz = (row & 3) ^ ((row >> 2) & 3);
            #pragma unroll
            for (int gg = 0; gg < 2; ++gg) {
                const int g = ((tid & 1) << 1) + gg;
                const float* src = B + (long)(n0 + row) * ldb + k0 + (g << 3);
                float v[8];
                *(float4*)&v[0] = *(const float4*)src;
                *(float4*)&v[4] = *(const float4*)(src + 4);
                unsigned hi[4], lo[4];
                split8(v, hi, lo);
                const int off = row * 32 + ((g ^ swz) << 3);
                *(uint4*)&Bh[off] = *(uint4*)hi;
                *(uint4*)&Bl[off] = *(uint4*)lo;
            }
        } else {
            const int n = tid & 127;
            const int swz = (n & 3) ^ ((n >> 2) & 3);
            #pragma unroll
            for (int gg = 0; gg < 2; ++gg) {
                const int g = ((tid >> 7) << 1) + gg;
                float v[8];
                #pragma unroll
                for (int e = 0; e < 8; ++e)
                    v[e] = B[(long)(k0 + (g << 3) + e) * ldb + n0 + n];
                unsigned hi[4], lo[4];
                split8(v, hi, lo);
                const int off = n * 32 + ((g ^ swz) << 3);
                *(uint4*)&Bh[off] = *(uint4*)hi;
                *(uint4*)&Bl[off] = *(uint4*)lo;
            }
        }
        __syncthreads();

        {
            const int r = lane & 15, g = lane >> 4;
            const int lswz = (r & 3) ^ ((r >> 2) & 3);
            const int gslot = ((g ^ lswz) << 3);
            const int abase = ((wr << 6) + r) * 32 + gslot;
            const int bbase = ((wc << 6) + r) * 32 + gslot;
            short8v afh[4], afl[4], bfh[4], bfl[4];
            #pragma unroll
            for (int f = 0; f < 4; ++f) {
                afh[f] = *(short8v*)&Ah[abase + f * 512];
                afl[f] = *(short8v*)&Al[abase + f * 512];
                bfh[f] = *(short8v*)&Bh[bbase + f * 512];
                bfl[f] = *(short8v*)&Bl[bbase + f * 512];
            }
            #pragma unroll
            for (int fi = 0; fi < 4; ++fi)
                #pragma unroll
                for (int fj = 0; fj < 4; ++fj) {
                    acc[fi][fj] = __builtin_amdgcn_mfma_f32_16x16x32_bf16(
                        afh[fi], bfh[fj], acc[fi][fj], 0, 0, 0);
                    acc[fi][fj] = __builtin_amdgcn_mfma_f32_16x16x32_bf16(
                        afh[fi], bfl[fj], acc[fi][fj], 0, 0, 0);
                    acc[fi][fj] = __builtin_amdgcn_mfma_f32_16x16x32_bf16(
                        afl[fi], bfh[fj], acc[fi][fj], 0, 0, 0);
                }
        }
        __syncthreads();
    }

    // C/D layout: col = lane&15, row = (lane>>4)*4 + reg  [m89/m91]
    const int r = lane & 15, g = lane >> 4;
    #pragma unroll
    for (int fi = 0; fi < 4; ++fi) {
        const int gr0 = m0 + (wr << 6) + fi * 16 + g * 4;
        #pragma unroll
        for (int fj = 0; fj < 4; ++fj) {
            const int gc = n0 + (wc << 6) + fj * 16 + r;
            #pragma unroll
            for (int qq = 0; qq < 4; ++qq)
                C[(long)(gr0 + qq) * ldc + gc] = acc[fi][fj][qq] * scale;
        }
    }
}

// ---------------------------------------------------------------------------
// Fused QKV projection via split-bf16 MFMA: x[2048x512] @ {Wq|Wk|Wv}[512x512]
// -> QKV [3][BH][512][64]. Grid (12, 16).
// ---------------------------------------------------------------------------
__global__ __launch_bounds__(256)
void gemm_qkv_mfma(const float* __restrict__ x, const float* __restrict__ Wq,
                   const float* __restrict__ Wk, const float* __restrict__ Wv,
                   float* __restrict__ QKV)
{
    const int m0 = blockIdx.y << 7;
    const int ng = blockIdx.x << 7;
    const float* __restrict__ W = (ng < 512) ? Wq : (ng < 1024) ? Wk : Wv;
    const int n0 = ng & 511;
    float* __restrict__ C = QKV + (long)(ng >> 9) * (1 << 20);

    __shared__ short Ah[128 * 32], Al[128 * 32], Bh[128 * 32], Bl[128 * 32];

    const int tid = threadIdx.x;
    const int lane = tid & 63, wv = tid >> 6;
    const int wr = wv >> 1, wc = wv & 1;

    f32x4 acc[4][4] = {};

    for (int k0 = 0; k0 < 512; k0 += 32) {
        {
            const int row = tid >> 1;
            const int swz = (row & 3) ^ ((row >> 2) & 3);
            #pragma unroll
            for (int gg = 0; gg < 2; ++gg) {
                const int g = ((tid & 1) << 1) + gg;
                const float* src = x + (long)(m0 + row) * 512 + k0 + (g << 3);
                float v[8];
                *(float4*)&v[0] = *(const float4*)src;
                *(float4*)&v[4] = *(const float4*)(src + 4);
                unsigned hi[4], lo[4];
                split8(v, hi, lo);
                const int off = row * 32 + ((g ^ swz) << 3);
                *(uint4*)&Ah[off] = *(uint4*)hi;
                *(uint4*)&Al[off] = *(uint4*)lo;
            }
        }
        {
            const int n = tid & 127;
            const int swz = (n & 3) ^ ((n >> 2) & 3);
            #pragma unroll
            for (int gg = 0; gg < 2; ++gg) {
                const int g = ((tid >> 7) << 1) + gg;
                float v[8];
                #pragma unroll
                for (int e = 0; e < 8; ++e)
                    v[e] = W[(long)(k0 + (g << 3) + e) * 512 + n0 + n];
                unsigned hi[4], lo[4];
                split8(v, hi, lo);
                const int off = n * 32 + ((g ^ swz) << 3);
                *(uint4*)&Bh[off] = *(uint4*)hi;
                *(uint4*)&Bl[off] = *(uint4*)lo;
            }
        }
        __syncthreads();

        {
            const int r = lane & 15, g = lane >> 4;
            const int lswz = (r & 3) ^ ((r >> 2) & 3);
            const int gslot = ((g ^ lswz) << 3);
            const int abase = ((wr << 6) + r) * 32 + gslot;
            const int bbase = ((wc << 6) + r) * 32 + gslot;
            short8v afh[4], afl[4], bfh[4], bfl[4];
            #pragma unroll
            for (int f = 0; f < 4; ++f) {
                afh[f] = *(short8v*)&Ah[abase + f * 512];
                afl[f] = *(short8v*)&Al[abase + f * 512];
                bfh[f] = *(short8v*)&Bh[bbase + f * 512];
                bfl[f] = *(short8v*)&Bl[bbase + f * 512];
            }
            #pragma unroll
            for (int fi = 0; fi < 4; ++fi)
                #pragma unroll
                for (int fj = 0; fj < 4; ++fj) {
                    acc[fi][fj] = __builtin_amdgcn_mfma_f32_16x16x32_bf16(
                        afh[fi], bfh[fj], acc[fi][fj], 0, 0, 0);
                    acc[fi][fj] = __builtin_amdgcn_mfma_f32_16x16x32_bf16(
                        afh[fi], bfl[fj], acc[fi][fj], 0, 0, 0);
                    acc[fi][fj] = __builtin_amdgcn_mfma_f32_16x16x32_bf16(
                        afl[fi], bfh[fj], acc[fi][fj], 0, 0, 0);
                }
        }
        __syncthreads();
    }

    const int r = lane & 15, g = lane >> 4;
    #pragma unroll
    for (int fi = 0; fi < 4; ++fi) {
        const int gr0 = m0 + (wr << 6) + fi * 16 + g * 4;
        #pragma unroll
        for (int fj = 0; fj < 4; ++fj) {
            const int nl = n0 + (wc << 6) + fj * 16 + r;
            const int h = nl >> 6, d = nl & 63;
            #pragma unroll
            for (int qq = 0; qq < 4; ++qq) {
                const int m = gr0 + qq;
                const int b = m >> 9, l = m & 511;
                C[((long)((b * 8 + h) * 512 + l)) * 64 + d] = acc[fi][fj][qq];
            }
        }
    }
}

// ---------------------------------------------------------------------------
// Adjacency v7 (R5 structure + fma/max/count inner loop):
//   A[i,k] = 2^-15 * sum_j u·[u > 6.4],  u = S_ij*S_kj, diag 0.
// Inner: d = fma(a,b,-6.4); T1 += max(d,0); neg-count via sign bit packed
// 4x8-bit (per-wave j<=128 so no byte overflow). Element value folded as
// T1 + 6.4*(128 - neg) per wave before the cross-wave LDS reduce.
// Membership flips vs reference only within half-ulp of 6.4 (~500 of 2.4e9
// products, ~2e-4 each on sparse A entries -> negligible at output).
// 64x64 tile, upper-tri tile pairs (36), mirrored write. 4 waves, each wave
// sums its private 128-j range with private LDS staging, no main-loop
// barriers. VGPR budget: T1 64 + cnt 16 + staging ~ <128 (the R6 cliff).
// ---------------------------------------------------------------------------
__global__ __launch_bounds__(256)
void adj_kernel(const float* __restrict__ S, float* __restrict__ A)
{
    const int bh = blockIdx.y;
    const float* __restrict__ Sh = S + (long)bh * 262144;
    float* __restrict__ Ah = A + (long)bh * 262144;

    int ti = 0, rem = blockIdx.x;
    while (rem >= 8 - ti) { rem -= 8 - ti; ++ti; }
    const int tk = ti + rem;
    const int i0 = ti << 6, k0 = tk << 6;

    __shared__ float smem[8704];        // 34816 B: staging 4x(2x16x68) / reduce

    const int tid  = threadIdx.x;
    const int lane = tid & 63;
    const int wv   = tid >> 6;
    const int ly8  = (lane >> 3) << 3;
    const int lx8  = (lane & 7) << 3;
    const int r4   = lane >> 2;          // 0..15
    const int q    = lane & 3;           // 0..3

    float (*stgL)[68] = (float(*)[68])&smem[wv * 2176];
    float (*stgR)[68] = (float(*)[68])&smem[wv * 2176 + 1088];

    const float nC = -6.4f;              // -(0.1f*64), exact pow2 scale of 0.1f

    float    T1[8][8] = {};
    unsigned cnt[8][2] = {};             // [i][j>>2], 4 packed byte counters

    const int jw = wv << 7;              // this wave's j base
    for (int c = 0; c < 8; ++c) {
        const int j0 = jw + (c << 4);
        float4 rl[4], rr[4];
        #pragma unroll
        for (int p = 0; p < 4; ++p) {
            rl[p] = *(const float4*)(Sh + (long)(i0 + r4 + (p << 4)) * 512 + j0 + (q << 2));
            rr[p] = *(const float4*)(Sh + (long)(k0 + r4 + (p << 4)) * 512 + j0 + (q << 2));
        }
        #pragma unroll
        for (int p = 0; p < 4; ++p) {
            const int row = r4 + (p << 4);
            stgL[(q << 2) + 0][row] = rl[p].x;
            stgL[(q << 2) + 1][row] = rl[p].y;
            stgL[(q << 2) + 2][row] = rl[p].z;
            stgL[(q << 2) + 3][row] = rl[p].w;
            stgR[(q << 2) + 0][row] = rr[p].x;
            stgR[(q << 2) + 1][row] = rr[p].y;
            stgR[(q << 2) + 2][row] = rr[p].z;
            stgR[(q << 2) + 3][row] = rr[p].w;
        }
        __builtin_amdgcn_s_waitcnt(0);   // wave-private staging: drain, no barrier
        #pragma unroll 4
        for (int jj = 0; jj < 16; ++jj) {
            float a[8], b[8];
            *(float4*)&a[0] = *(const float4*)&stgL[jj][ly8];
            *(float4*)&a[4] = *(const float4*)&stgL[jj][ly8 + 4];
            *(float4*)&b[0] = *(const float4*)&stgR[jj][lx8];
            *(float4*)&b[4] = *(const float4*)&stgR[jj][lx8 + 4];
            #pragma unroll
            for (int i = 0; i < 8; ++i)
                #pragma unroll
                for (int j = 0; j < 8; ++j) {
                    const float d = fmaf(a[i], b[j], nC);
                    T1[i][j] += fmaxf(d, 0.0f);
                    cnt[i][j >> 2] += (((unsigned)__float_as_int(d)) >> 31) << ((j & 3) << 3);
                }
        }
    }

    // fold count into value: elem = T1 + 6.4*(128 - neg)
    #pragma unroll
    for (int i = 0; i < 8; ++i)
        #pragma unroll
        for (int j = 0; j < 8; ++j) {
            const unsigned neg = (cnt[i][j >> 2] >> ((j & 3) << 3)) & 255u;
            T1[i][j] = fmaf(6.4f, (float)(128u - neg), T1[i][j]);
        }

    // ---- 3-phase reduce: (w0+w1) + (w3+w2), result in wave 0 ----
    float* red0 = &smem[0];
    float* red1 = &smem[4352];

    __syncthreads();
    if (wv == 1 || wv == 2) {
        float* dst = (wv == 1 ? red0 : red1) + lane * 68;
        #pragma unroll
        for (int i = 0; i < 8; ++i) {
            *(float4*)(dst + i * 8)     = *(float4*)&T1[i][0];
            *(float4*)(dst + i * 8 + 4) = *(float4*)&T1[i][4];
        }
    }
    __syncthreads();
    if (wv == 0 || wv == 3) {
        const float* src = (wv == 0 ? red0 : red1) + lane * 68;
        #pragma unroll
        for (int i = 0; i < 8; ++i) {
            float4 p0 = *(const float4*)(src + i * 8);
            float4 p1 = *(const float4*)(src + i * 8 + 4);
            T1[i][0] += p0.x; T1[i][1] += p0.y; T1[i][2] += p0.z; T1[i][3] += p0.w;
            T1[i][4] += p1.x; T1[i][5] += p1.y; T1[i][6] += p1.z; T1[i][7] += p1.w;
        }
    }
    __syncthreads();
    if (wv == 3) {
        float* dst = red0 + lane * 68;
        #pragma unroll
        for (int i = 0; i < 8; ++i) {
            *(float4*)(dst + i * 8)     = *(float4*)&T1[i][0];
            *(float4*)(dst + i * 8 + 4) = *(float4*)&T1[i][4];
        }
    }
    __syncthreads();
    if (wv == 0) {
        const float* src = red0 + lane * 68;
        const float SC = 1.0f / 32768.0f;    // 2^-15 exact
        float f[8][8];
        #pragma unroll
        for (int i = 0; i < 8; ++i) {
            float4 p0 = *(const float4*)(src + i * 8);
            float4 p1 = *(const float4*)(src + i * 8 + 4);
            f[i][0] = (T1[i][0] + p0.x) * SC;
            f[i][1] = (T1[i][1] + p0.y) * SC;
            f[i][2] = (T1[i][2] + p0.z) * SC;
            f[i][3] = (T1[i][3] + p0.w) * SC;
            f[i][4] = (T1[i][4] + p1.x) * SC;
            f[i][5] = (T1[i][5] + p1.y) * SC;
            f[i][6] = (T1[i][6] + p1.z) * SC;
            f[i][7] = (T1[i][7] + p1.w) * SC;
        }
        if (ti == tk) {
            #pragma unroll
            for (int i = 0; i < 8; ++i)
                #pragma unroll
                for (int j = 0; j < 8; ++j)
                    if (ly8 + i == lx8 + j) f[i][j] = 0.0f;
        }
        #pragma unroll
        for (int i = 0; i < 8; ++i) {
            float* dst = Ah + (long)(i0 + ly8 + i) * 512 + k0 + lx8;
            *(float4*)dst       = make_float4(f[i][0], f[i][1], f[i][2], f[i][3]);
            *(float4*)(dst + 4) = make_float4(f[i][4], f[i][5], f[i][6], f[i][7]);
        }
        if (ti != tk) {
            #pragma unroll
            for (int j = 0; j < 8; ++j) {
                float* dst = Ah + (long)(k0 + lx8 + j) * 512 + i0 + ly8;
                *(float4*)dst       = make_float4(f[0][j], f[1][j], f[2][j], f[3][j]);
                *(float4*)(dst + 4) = make_float4(f[4][j], f[5][j], f[6][j], f[7][j]);
            }
        }
    }
}

// ---------------------------------------------------------------------------
// Row degree: R[row] = 1/sqrt(clip(1 + sum_k A[row,k], 1e-6))
// ---------------------------------------------------------------------------
__global__ __launch_bounds__(256)
void rowsum_kernel(const float* __restrict__ A, float* __restrict__ R)
{
    const int row = (blockIdx.x << 2) + (threadIdx.x >> 6);
    const int lane = threadIdx.x & 63;
    const float* p = A + (long)row * 512;
    float s = 0.0f;
    #pragma unroll
    for (int t = 0; t < 8; ++t) s += p[lane + (t << 6)];
    #pragma unroll
    for (int off = 32; off; off >>= 1) s += __shfl_xor(s, off, 64);
    if (lane == 0) R[row] = 1.0f / sqrtf(fmaxf(1.0f + s, 1e-6f));
}

// ---------------------------------------------------------------------------
// A_hat[i,k] = R[i]*R[k]*(A[i,k] + (i==k)) in place
// ---------------------------------------------------------------------------
__global__ __launch_bounds__(256)
void ahat_kernel(float* __restrict__ A, const float* __restrict__ R)
{
    const long i4 = ((long)blockIdx.x * 256 + threadIdx.x) << 2;
    const long off = i4 & 262143;
    const long bh = i4 >> 18;
    const int i = (int)(off >> 9);
    const int k = (int)(off & 511);
    const float ri = R[(bh << 9) + i];
    const float* Rk = R + (bh << 9) + k;
    float4 v = *(float4*)(A + i4);
    v.x = ri * Rk[0] * (v.x + ((k + 0) == i ? 1.0f : 0.0f));
    v.y = ri * Rk[1] * (v.y + ((k + 1) == i ? 1.0f : 0.0f));
    v.z = ri * Rk[2] * (v.z + ((k + 2) == i ? 1.0f : 0.0f));
    v.w = ri * Rk[3] * (v.w + ((k + 3) == i ? 1.0f : 0.0f));
    *(float4*)(A + i4) = v;
}

// ---------------------------------------------------------------------------
// Row softmax over 512, in place. Wave per row, 4 rows/block, no barriers.
// ---------------------------------------------------------------------------
__global__ __launch_bounds__(256)
void softmax_kernel(float* __restrict__ P)
{
    const int row = (blockIdx.x << 2) + (threadIdx.x >> 6);
    const int lane = threadIdx.x & 63;
    float* p = P + (long)row * 512 + (lane << 3);
    float4 v0 = *(float4*)p;
    float4 v1 = *(float4*)(p + 4);
    float mx = fmaxf(fmaxf(fmaxf(v0.x, v0.y), fmaxf(v0.z, v0.w)),
                     fmaxf(fmaxf(v1.x, v1.y), fmaxf(v1.z, v1.w)));
    #pragma unroll
    for (int off = 32; off; off >>= 1) mx = fmaxf(mx, __shfl_xor(mx, off, 64));
    float e[8];
    e[0] = __expf(v0.x - mx); e[1] = __expf(v0.y - mx);
    e[2] = __expf(v0.z - mx); e[3] = __expf(v0.w - mx);
    e[4] = __expf(v1.x - mx); e[5] = __expf(v1.y - mx);
    e[6] = __expf(v1.z - mx); e[7] = __expf(v1.w - mx);
    float s = (((e[0] + e[1]) + (e[2] + e[3])) + ((e[4] + e[5]) + (e[6] + e[7])));
    #pragma unroll
    for (int off = 32; off; off >>= 1) s += __shfl_xor(s, off, 64);
    const float inv = 1.0f / s;
    *(float4*)p       = make_float4(e[0] * inv, e[1] * inv, e[2] * inv, e[3] * inv);
    *(float4*)(p + 4) = make_float4(e[4] * inv, e[5] * inv, e[6] * inv, e[7] * inv);
}

// ---------------------------------------------------------------------------
// O = P @ V per head via split-bf16 MFMA, writing DIRECTLY to Of layout
// [B][L][H*HD]. M=512, N=64, K=512. 128x64 tile, 4 waves stacked on M.
// Grid (1, 4, 32).
// ---------------------------------------------------------------------------
__global__ __launch_bounds__(256)
void gemm_pv_mfma(const float* __restrict__ P, const float* __restrict__ V,
                  float* __restrict__ Of)
{
    const int bh = blockIdx.z;
    const float* __restrict__ Pp = P + (long)bh * 262144;
    const float* __restrict__ Vp = V + (long)bh * 32768;
    const int bb = bh >> 3, hh = bh & 7;
    const int m0 = blockIdx.y << 7;

    __shared__ short Ph[128 * 32], Pl[128 * 32], Vh[64 * 32], Vl[64 * 32];

    const int tid = threadIdx.x;
    const int lane = tid & 63, wv = tid >> 6;

    f32x4 acc[2][4] = {};

    for (int k0 = 0; k0 < 512; k0 += 32) {
        {
            const int row = tid >> 1;
            const int swz = (row & 3) ^ ((row >> 2) & 3);
            #pragma unroll
            for (int gg = 0; gg < 2; ++gg) {
                const int g = ((tid & 1) << 1) + gg;
                const float* src = Pp + (long)(m0 + row) * 512 + k0 + (g << 3);
                float v[8];
                *(float4*)&v[0] = *(const float4*)src;
                *(float4*)&v[4] = *(const float4*)(src + 4);
                unsigned hi[4], lo[4];
                split8(v, hi, lo);
                const int off = row * 32 + ((g ^ swz) << 3);
                *(uint4*)&Ph[off] = *(uint4*)hi;
                *(uint4*)&Pl[off] = *(uint4*)lo;
            }
        }
        {
            const int n = tid & 63, g = tid >> 6;
            const int swz = (n & 3) ^ ((n >> 2) & 3);
            float v[8];
            #pragma unroll
            for (int e = 0; e < 8; ++e)
                v[e] = Vp[(long)(k0 + (g << 3) + e) * 64 + n];
            unsigned hi[4], lo[4];
            split8(v, hi, lo);
            const int off = n * 32 + ((g ^ swz) << 3);
            *(uint4*)&Vh[off] = *(uint4*)hi;
            *(uint4*)&Vl[off] = *(uint4*)lo;
        }
        __syncthreads();

        {
            const int r = lane & 15, g = lane >> 4;
            const int lswz = (r & 3) ^ ((r >> 2) & 3);
            const int gslot = ((g ^ lswz) << 3);
            short8v afh[2], afl[2], bfh[4], bfl[4];
            #pragma unroll
            for (int fi = 0; fi < 2; ++fi) {
                const int abase = ((wv << 5) + (fi << 4) + r) * 32 + gslot;
                afh[fi] = *(short8v*)&Ph[abase];
                afl[fi] = *(short8v*)&Pl[abase];
            }
            #pragma unroll
            for (int fj = 0; fj < 4; ++fj) {
                const int bbase = ((fj << 4) + r) * 32 + gslot;
                bfh[fj] = *(short8v*)&Vh[bbase];
                bfl[fj] = *(short8v*)&Vl[bbase];
            }
            #pragma unroll
            for (int fi = 0; fi < 2; ++fi)
                #pragma unroll
                for (int fj = 0; fj < 4; ++fj) {
                    acc[fi][fj] = __builtin_amdgcn_mfma_f32_16x16x32_bf16(
                        afh[fi], bfh[fj], acc[fi][fj], 0, 0, 0);
                    acc[fi][fj] = __builtin_amdgcn_mfma_f32_16x16x32_bf16(
                        afh[fi], bfl[fj], acc[fi][fj], 0, 0, 0);
                    acc[fi][fj] = __builtin_amdgcn_mfma_f32_16x16x32_bf16(
                        afl[fi], bfh[fj], acc[fi][fj], 0, 0, 0);
                }
        }
        __syncthreads();
    }

    const int r = lane & 15, g = lane >> 4;
    #pragma unroll
    for (int fi = 0; fi < 2; ++fi) {
        const int l0 = m0 + (wv << 5) + fi * 16 + g * 4;
        #pragma unroll
        for (int fj = 0; fj < 4; ++fj) {
            const int d = fj * 16 + r;
            #pragma unroll
            for (int qq = 0; qq < 4; ++qq)
                Of[((long)((bb << 9) + l0 + qq) << 9) + (hh << 6) + d] = acc[fi][fj][qq];
        }
    }
}

// ---------------------------------------------------------------------------
extern "C" void kernel_launch(void* const* d_in, const int* in_sizes, int n_in,
                              void* d_out, int out_size, void* d_ws, size_t ws_size,
                              hipStream_t stream)
{
    const float* x  = (const float*)d_in[0];
    const float* Wq = (const float*)d_in[1];
    const float* Wk = (const float*)d_in[2];
    const float* Wv = (const float*)d_in[3];
    const float* Wo = (const float*)d_in[4];
    float* out = (float*)d_out;

    float* ws = (float*)d_ws;
    float* Q  = ws;                       // 1M floats (QKV base; later Of)
    float* Kt = Q  + (1u << 20);          // 1M
    float* V  = Kt + (1u << 20);          // 1M
    float* S  = V  + (1u << 20);          // 8M
    float* Am = S  + (8u << 20);          // 8M (adjacency -> A_hat)
    float* T  = Am + (8u << 20);          // 8M (A_hat@S temp)
    float* R  = T  + (8u << 20);          // 16K

    dim3 blk(256);

    // 1) fused QKV projections (split-bf16 MFMA)
    gemm_qkv_mfma<<<dim3(12, 16, 1), blk, 0, stream>>>(x, Wq, Wk, Wv, Q);

    // 2) S = Q K^T per head (MFMA, K=64)
    gemm_mfma<1><<<dim3(4, 4, 32), blk, 0, stream>>>(Q, Kt, S, 64, 64, 64, 512,
                                                     32768, 32768, 262144, 1.0f);

    // 3) adjacency (R5 structure, fma/max/count inner loop)
    adj_kernel<<<dim3(36, 32), blk, 0, stream>>>(S, Am);

    // 4) row degrees -> R
    rowsum_kernel<<<dim3(4096), blk, 0, stream>>>(Am, R);

    // 5) A_hat in place
    ahat_kernel<<<dim3(8192), blk, 0, stream>>>(Am, R);

    // 6) T = A_hat @ S (MFMA)
    gemm_mfma<0><<<dim3(4, 4, 32), blk, 0, stream>>>(Am, S, T, 512, 512, 512, 512,
                                                     262144, 262144, 262144, 1.0f);

    // 7) J = T @ A_hat^T / 8 -> S (MFMA)
    gemm_mfma<1><<<dim3(4, 4, 32), blk, 0, stream>>>(T, Am, S, 512, 512, 512, 512,
                                                     262144, 262144, 262144, 0.125f);

    // 8) softmax rows of J (wave per row)
    softmax_kernel<<<dim3(4096), blk, 0, stream>>>(S);

    // 9) O = P @ V -> Of directly (reuse Q buffer)
    gemm_pv_mfma<<<dim3(1, 4, 32), blk, 0, stream>>>(S, V, Q);

    // 10) out = Of @ Wo (MFMA)
    gemm_mfma<0><<<dim3(4, 16, 1), blk, 0, stream>>>(Q, Wo, out, 512, 512, 512, 512,
                                                     0, 0, 0, 1.0f);
}

// Round 10
// 439.102 us; speedup vs baseline: 1.5096x; 1.2226x over previous
//
#include <hip/hip_runtime.h>
#include <math.h>

// Problem constants: B=4, H=8, L=512, HD=64, D=512, RHO=0.1
// Workspace (floats):
//   Q   : 1M   [BH][512][64]   (QKV base; later reused as Of [B][L][512])
//   Kt  : 1M
//   V   : 1M
//   S   : 8M   [BH][512][512]  (scores -> later J -> softmax'd P)
//   Am  : 8M   (adjacency -> A_hat in place)
//   T   : 8M   (A_hat@S temp)
//   R   : 16K  (row inv-sqrt degrees)

typedef __attribute__((ext_vector_type(8))) short short8v;
typedef __attribute__((ext_vector_type(4))) float f32x4;
typedef _Float16 h2 __attribute__((ext_vector_type(2)));

// ---------------------------------------------------------------------------
// bf16 split helper: pack 8 fp32 -> hi/lo bf16x8 (truncation split)
// ---------------------------------------------------------------------------
__device__ __forceinline__ void split8(const float* v, unsigned* hi, unsigned* lo)
{
    #pragma unroll
    for (int q = 0; q < 4; ++q) {
        const unsigned b0 = __float_as_uint(v[2 * q])     & 0xFFFF0000u;
        const unsigned b1 = __float_as_uint(v[2 * q + 1]) & 0xFFFF0000u;
        const float d0 = v[2 * q]     - __uint_as_float(b0);
        const float d1 = v[2 * q + 1] - __uint_as_float(b1);
        hi[q] = (b0 >> 16) | b1;
        lo[q] = (__float_as_uint(d0) >> 16) | (__float_as_uint(d1) & 0xFFFF0000u);
    }
}

// ---------------------------------------------------------------------------
// Split-bf16 MFMA GEMM. 128x128 tile, 256 threads (4 waves 2x2), K-step 32.
// BT=0: C = A @ B; BT=1: C = A @ B^T. acc = Ahi*Bhi + Ahi*Blo + Alo*Bhi.
// ---------------------------------------------------------------------------
template<int BT>
__global__ __launch_bounds__(256)
void gemm_mfma(const float* __restrict__ Ap, const float* __restrict__ Bp,
               float* __restrict__ Cp, int K, int lda, int ldb, int ldc,
               long sA, long sB, long sC, float scale)
{
    const float* __restrict__ A = Ap + (long)blockIdx.z * sA;
    const float* __restrict__ B = Bp + (long)blockIdx.z * sB;
    float* __restrict__ C = Cp + (long)blockIdx.z * sC;
    const int m0 = blockIdx.y << 7, n0 = blockIdx.x << 7;

    __shared__ short Ah[128 * 32], Al[128 * 32], Bh[128 * 32], Bl[128 * 32];

    const int tid = threadIdx.x;
    const int lane = tid & 63, wv = tid >> 6;
    const int wr = wv >> 1, wc = wv & 1;

    f32x4 acc[4][4] = {};

    for (int k0 = 0; k0 < K; k0 += 32) {
        {
            const int row = tid >> 1;
            const int swz = (row & 3) ^ ((row >> 2) & 3);
            #pragma unroll
            for (int gg = 0; gg < 2; ++gg) {
                const int g = ((tid & 1) << 1) + gg;
                const float* src = A + (long)(m0 + row) * lda + k0 + (g << 3);
                float v[8];
                *(float4*)&v[0] = *(const float4*)src;
                *(float4*)&v[4] = *(const float4*)(src + 4);
                unsigned hi[4], lo[4];
                split8(v, hi, lo);
                const int off = row * 32 + ((g ^ swz) << 3);
                *(uint4*)&Ah[off] = *(uint4*)hi;
                *(uint4*)&Al[off] = *(uint4*)lo;
            }
        }
        if (BT) {
            const int row = tid >> 1;
            const int swz = (row & 3) ^ ((row >> 2) & 3);
            #pragma unroll
            for (int gg = 0; gg < 2; ++gg) {
                const int g = ((tid & 1) << 1) + gg;
                const float* src = B + (long)(n0 + row) * ldb + k0 + (g << 3);
                float v[8];
                *(float4*)&v[0] = *(const float4*)src;
                *(float4*)&v[4] = *(const float4*)(src + 4);
                unsigned hi[4], lo[4];
                split8(v, hi, lo);
                const int off = row * 32 + ((g ^ swz) << 3);
                *(uint4*)&Bh[off] = *(uint4*)hi;
                *(uint4*)&Bl[off] = *(uint4*)lo;
            }
        } else {
            const int n = tid & 127;
            const int swz = (n & 3) ^ ((n >> 2) & 3);
            #pragma unroll
            for (int gg = 0; gg < 2; ++gg) {
                const int g = ((tid >> 7) << 1) + gg;
                float v[8];
                #pragma unroll
                for (int e = 0; e < 8; ++e)
                    v[e] = B[(long)(k0 + (g << 3) + e) * ldb + n0 + n];
                unsigned hi[4], lo[4];
                split8(v, hi, lo);
                const int off = n * 32 + ((g ^ swz) << 3);
                *(uint4*)&Bh[off] = *(uint4*)hi;
                *(uint4*)&Bl[off] = *(uint4*)lo;
            }
        }
        __syncthreads();

        {
            const int r = lane & 15, g = lane >> 4;
            const int lswz = (r & 3) ^ ((r >> 2) & 3);
            const int gslot = ((g ^ lswz) << 3);
            const int abase = ((wr << 6) + r) * 32 + gslot;
            const int bbase = ((wc << 6) + r) * 32 + gslot;
            short8v afh[4], afl[4], bfh[4], bfl[4];
            #pragma unroll
            for (int f = 0; f < 4; ++f) {
                afh[f] = *(short8v*)&Ah[abase + f * 512];
                afl[f] = *(short8v*)&Al[abase + f * 512];
                bfh[f] = *(short8v*)&Bh[bbase + f * 512];
                bfl[f] = *(short8v*)&Bl[bbase + f * 512];
            }
            #pragma unroll
            for (int fi = 0; fi < 4; ++fi)
                #pragma unroll
                for (int fj = 0; fj < 4; ++fj) {
                    acc[fi][fj] = __builtin_amdgcn_mfma_f32_16x16x32_bf16(
                        afh[fi], bfh[fj], acc[fi][fj], 0, 0, 0);
                    acc[fi][fj] = __builtin_amdgcn_mfma_f32_16x16x32_bf16(
                        afh[fi], bfl[fj], acc[fi][fj], 0, 0, 0);
                    acc[fi][fj] = __builtin_amdgcn_mfma_f32_16x16x32_bf16(
                        afl[fi], bfh[fj], acc[fi][fj], 0, 0, 0);
                }
        }
        __syncthreads();
    }

    // C/D layout: col = lane&15, row = (lane>>4)*4 + reg  [m89/m91]
    const int r = lane & 15, g = lane >> 4;
    #pragma unroll
    for (int fi = 0; fi < 4; ++fi) {
        const int gr0 = m0 + (wr << 6) + fi * 16 + g * 4;
        #pragma unroll
        for (int fj = 0; fj < 4; ++fj) {
            const int gc = n0 + (wc << 6) + fj * 16 + r;
            #pragma unroll
            for (int qq = 0; qq < 4; ++qq)
                C[(long)(gr0 + qq) * ldc + gc] = acc[fi][fj][qq] * scale;
        }
    }
}

// ---------------------------------------------------------------------------
// Fused QKV projection via split-bf16 MFMA: x[2048x512] @ {Wq|Wk|Wv}[512x512]
// -> QKV [3][BH][512][64]. Grid (12, 16).
// ---------------------------------------------------------------------------
__global__ __launch_bounds__(256)
void gemm_qkv_mfma(const float* __restrict__ x, const float* __restrict__ Wq,
                   const float* __restrict__ Wk, const float* __restrict__ Wv,
                   float* __restrict__ QKV)
{
    const int m0 = blockIdx.y << 7;
    const int ng = blockIdx.x << 7;
    const float* __restrict__ W = (ng < 512) ? Wq : (ng < 1024) ? Wk : Wv;
    const int n0 = ng & 511;
    float* __restrict__ C = QKV + (long)(ng >> 9) * (1 << 20);

    __shared__ short Ah[128 * 32], Al[128 * 32], Bh[128 * 32], Bl[128 * 32];

    const int tid = threadIdx.x;
    const int lane = tid & 63, wv = tid >> 6;
    const int wr = wv >> 1, wc = wv & 1;

    f32x4 acc[4][4] = {};

    for (int k0 = 0; k0 < 512; k0 += 32) {
        {
            const int row = tid >> 1;
            const int swz = (row & 3) ^ ((row >> 2) & 3);
            #pragma unroll
            for (int gg = 0; gg < 2; ++gg) {
                const int g = ((tid & 1) << 1) + gg;
                const float* src = x + (long)(m0 + row) * 512 + k0 + (g << 3);
                float v[8];
                *(float4*)&v[0] = *(const float4*)src;
                *(float4*)&v[4] = *(const float4*)(src + 4);
                unsigned hi[4], lo[4];
                split8(v, hi, lo);
                const int off = row * 32 + ((g ^ swz) << 3);
                *(uint4*)&Ah[off] = *(uint4*)hi;
                *(uint4*)&Al[off] = *(uint4*)lo;
            }
        }
        {
            const int n = tid & 127;
            const int swz = (n & 3) ^ ((n >> 2) & 3);
            #pragma unroll
            for (int gg = 0; gg < 2; ++gg) {
                const int g = ((tid >> 7) << 1) + gg;
                float v[8];
                #pragma unroll
                for (int e = 0; e < 8; ++e)
                    v[e] = W[(long)(k0 + (g << 3) + e) * 512 + n0 + n];
                unsigned hi[4], lo[4];
                split8(v, hi, lo);
                const int off = n * 32 + ((g ^ swz) << 3);
                *(uint4*)&Bh[off] = *(uint4*)hi;
                *(uint4*)&Bl[off] = *(uint4*)lo;
            }
        }
        __syncthreads();

        {
            const int r = lane & 15, g = lane >> 4;
            const int lswz = (r & 3) ^ ((r >> 2) & 3);
            const int gslot = ((g ^ lswz) << 3);
            const int abase = ((wr << 6) + r) * 32 + gslot;
            const int bbase = ((wc << 6) + r) * 32 + gslot;
            short8v afh[4], afl[4], bfh[4], bfl[4];
            #pragma unroll
            for (int f = 0; f < 4; ++f) {
                afh[f] = *(short8v*)&Ah[abase + f * 512];
                afl[f] = *(short8v*)&Al[abase + f * 512];
                bfh[f] = *(short8v*)&Bh[bbase + f * 512];
                bfl[f] = *(short8v*)&Bl[bbase + f * 512];
            }
            #pragma unroll
            for (int fi = 0; fi < 4; ++fi)
                #pragma unroll
                for (int fj = 0; fj < 4; ++fj) {
                    acc[fi][fj] = __builtin_amdgcn_mfma_f32_16x16x32_bf16(
                        afh[fi], bfh[fj], acc[fi][fj], 0, 0, 0);
                    acc[fi][fj] = __builtin_amdgcn_mfma_f32_16x16x32_bf16(
                        afh[fi], bfl[fj], acc[fi][fj], 0, 0, 0);
                    acc[fi][fj] = __builtin_amdgcn_mfma_f32_16x16x32_bf16(
                        afl[fi], bfh[fj], acc[fi][fj], 0, 0, 0);
                }
        }
        __syncthreads();
    }

    const int r = lane & 15, g = lane >> 4;
    #pragma unroll
    for (int fi = 0; fi < 4; ++fi) {
        const int gr0 = m0 + (wr << 6) + fi * 16 + g * 4;
        #pragma unroll
        for (int fj = 0; fj < 4; ++fj) {
            const int nl = n0 + (wc << 6) + fj * 16 + r;
            const int h = nl >> 6, d = nl & 63;
            #pragma unroll
            for (int qq = 0; qq < 4; ++qq) {
                const int m = gr0 + qq;
                const int b = m >> 9, l = m & 511;
                C[((long)((b * 8 + h) * 512 + l)) * 64 + d] = acc[fi][fj][qq];
            }
        }
    }
}

// ---------------------------------------------------------------------------
// Adjacency v8b: packed-fp16 inner loop (clang native _Float16 vectors).
//   A[i,k] = 2^-15 * sum_j u·[u > 6.4],  u = S_ij*S_kj, diag 0.
// Per j-PAIR (h2): d = a*b - 6.4; t = max(d,0);
//   m = min(t*32768 + t, t + 6.4)      // = (t>0) ? t+6.4 : 0
//   acc += m                           // 6 packed ops / 2 products
// (t*32768 overflows to inf for large t -> min picks t+6.4; t=0 -> 0;
//  mis-weight band only t<2e-4, ~15x narrower than fp16 rounding band.)
// fp16 rounding flips decisions within ~|u-6.4|<0.007 -> est <=1e-4 at output.
// 64x64 tile, upper-tri tile pairs (36), mirrored write. 4 waves, each wave
// sums its private 128-j range, private half2 LDS staging (17.4KB total),
// no main-loop barriers. Quarter-wise fp32 LDS tree reduce, VGPR ~100.
// ---------------------------------------------------------------------------
__global__ __launch_bounds__(256)
void adj_kernel(const float* __restrict__ S, float* __restrict__ A)
{
    const int bh = blockIdx.y;
    const float* __restrict__ Sh = S + (long)bh * 262144;
    float* __restrict__ Ah = A + (long)bh * 262144;

    int ti = 0, rem = blockIdx.x;
    while (rem >= 8 - ti) { rem -= 8 - ti; ++ti; }
    const int tk = ti + rem;
    const int i0 = ti << 6, k0 = tk << 6;

    __shared__ __align__(16) char smem_raw[17408];   // 4 waves x 2 sides x [8][68] h2

    const int tid  = threadIdx.x;
    const int lane = tid & 63;
    const int wv   = tid >> 6;
    const int ly8  = (lane >> 3) << 3;
    const int lx8  = (lane & 7) << 3;
    const int r4   = lane >> 2;          // 0..15 row group
    const int q    = lane & 3;           // 0..3 j-quad

    h2 (*stgL)[68] = (h2(*)[68])(smem_raw + wv * 4352);
    h2 (*stgR)[68] = (h2(*)[68])(smem_raw + wv * 4352 + 2176);

    const h2 nC2  = { (_Float16)(-6.4f), (_Float16)(-6.4f) };
    const h2 z2   = { (_Float16)0.0f,    (_Float16)0.0f };
    const h2 big2 = { (_Float16)32768.0f,(_Float16)32768.0f };
    const h2 c2   = { (_Float16)6.4f,    (_Float16)6.4f };

    h2 acc2[8][8];
    #pragma unroll
    for (int i = 0; i < 8; ++i)
        #pragma unroll
        for (int j = 0; j < 8; ++j)
            acc2[i][j] = z2;

    const int jw = wv << 7;              // this wave's j base
    for (int c = 0; c < 8; ++c) {
        const int j0 = jw + (c << 4);
        float4 rl[4], rr[4];
        #pragma unroll
        for (int p = 0; p < 4; ++p) {
            rl[p] = *(const float4*)(Sh + (long)(i0 + r4 + (p << 4)) * 512 + j0 + (q << 2));
            rr[p] = *(const float4*)(Sh + (long)(k0 + r4 + (p << 4)) * 512 + j0 + (q << 2));
        }
        #pragma unroll
        for (int p = 0; p < 4; ++p) {
            const int row = r4 + (p << 4);
            h2 h0, h1;
            h0[0] = (_Float16)rl[p].x; h0[1] = (_Float16)rl[p].y;
            h1[0] = (_Float16)rl[p].z; h1[1] = (_Float16)rl[p].w;
            stgL[(q << 1) + 0][row] = h0;
            stgL[(q << 1) + 1][row] = h1;
            h0[0] = (_Float16)rr[p].x; h0[1] = (_Float16)rr[p].y;
            h1[0] = (_Float16)rr[p].z; h1[1] = (_Float16)rr[p].w;
            stgR[(q << 1) + 0][row] = h0;
            stgR[(q << 1) + 1][row] = h1;
        }
        __builtin_amdgcn_s_waitcnt(0);   // wave-private staging: drain, no barrier
        #pragma unroll
        for (int jp = 0; jp < 8; ++jp) {
            h2 a2[8], b2[8];
            *(uint4*)&a2[0] = *(const uint4*)&stgL[jp][ly8];
            *(uint4*)&a2[4] = *(const uint4*)&stgL[jp][ly8 + 4];
            *(uint4*)&b2[0] = *(const uint4*)&stgR[jp][lx8];
            *(uint4*)&b2[4] = *(const uint4*)&stgR[jp][lx8 + 4];
            #pragma unroll
            for (int i = 0; i < 8; ++i)
                #pragma unroll
                for (int j = 0; j < 8; ++j) {
                    const h2 d = a2[i] * b2[j] + nC2;
                    const h2 t = __builtin_elementwise_max(d, z2);
                    const h2 m = __builtin_elementwise_min(t * big2 + t, t + c2);
                    acc2[i][j] += m;
                }
        }
    }

    // ---- quarter-wise fp32 reduce: (w0+w1)+(w3+w2) -> wave 0 ----
    float* buf0 = (float*)smem_raw;                   // 64 x 17 floats
    float* buf1 = (float*)(smem_raw + 4352);
    float  f[8][8];                                   // wv0's final totals

    #pragma unroll
    for (int qp = 0; qp < 4; ++qp) {
        float v[16];
        #pragma unroll
        for (int e = 0; e < 16; ++e) {
            const h2 hh = acc2[(qp << 1) + (e >> 3)][e & 7];
            v[e] = (float)hh[0] + (float)hh[1];
        }
        __syncthreads();
        if (wv == 1 || wv == 2) {
            float* dst = (wv == 1 ? buf0 : buf1) + lane * 17;
            #pragma unroll
            for (int e = 0; e < 16; ++e) dst[e] = v[e];
        }
        __syncthreads();
        if (wv == 0 || wv == 3) {
            const float* src = (wv == 0 ? buf0 : buf1) + lane * 17;
            #pragma unroll
            for (int e = 0; e < 16; ++e) v[e] += src[e];
        }
        __syncthreads();
        if (wv == 3) {
            float* dst = buf0 + lane * 17;
            #pragma unroll
            for (int e = 0; e < 16; ++e) dst[e] = v[e];
        }
        __syncthreads();
        if (wv == 0) {
            const float* src = buf0 + lane * 17;
            #pragma unroll
            for (int e = 0; e < 16; ++e)
                f[(qp << 1) + (e >> 3)][e & 7] = v[e] + src[e];
        }
    }

    if (wv == 0) {
        const float SC = 1.0f / 32768.0f;    // 2^-15 = (1/64)*(1/512), exact
        #pragma unroll
        for (int i = 0; i < 8; ++i)
            #pragma unroll
            for (int j = 0; j < 8; ++j)
                f[i][j] *= SC;
        if (ti == tk) {
            #pragma unroll
            for (int i = 0; i < 8; ++i)
                #pragma unroll
                for (int j = 0; j < 8; ++j)
                    if (ly8 + i == lx8 + j) f[i][j] = 0.0f;
        }
        #pragma unroll
        for (int i = 0; i < 8; ++i) {
            float* dst = Ah + (long)(i0 + ly8 + i) * 512 + k0 + lx8;
            *(float4*)dst       = make_float4(f[i][0], f[i][1], f[i][2], f[i][3]);
            *(float4*)(dst + 4) = make_float4(f[i][4], f[i][5], f[i][6], f[i][7]);
        }
        if (ti != tk) {
            #pragma unroll
            for (int j = 0; j < 8; ++j) {
                float* dst = Ah + (long)(k0 + lx8 + j) * 512 + i0 + ly8;
                *(float4*)dst       = make_float4(f[0][j], f[1][j], f[2][j], f[3][j]);
                *(float4*)(dst + 4) = make_float4(f[4][j], f[5][j], f[6][j], f[7][j]);
            }
        }
    }
}

// ---------------------------------------------------------------------------
// Row degree: R[row] = 1/sqrt(clip(1 + sum_k A[row,k], 1e-6))
// ---------------------------------------------------------------------------
__global__ __launch_bounds__(256)
void rowsum_kernel(const float* __restrict__ A, float* __restrict__ R)
{
    const int row = (blockIdx.x << 2) + (threadIdx.x >> 6);
    const int lane = threadIdx.x & 63;
    const float* p = A + (long)row * 512;
    float s = 0.0f;
    #pragma unroll
    for (int t = 0; t < 8; ++t) s += p[lane + (t << 6)];
    #pragma unroll
    for (int off = 32; off; off >>= 1) s += __shfl_xor(s, off, 64);
    if (lane == 0) R[row] = 1.0f / sqrtf(fmaxf(1.0f + s, 1e-6f));
}

// ---------------------------------------------------------------------------
// A_hat[i,k] = R[i]*R[k]*(A[i,k] + (i==k)) in place
// ---------------------------------------------------------------------------
__global__ __launch_bounds__(256)
void ahat_kernel(float* __restrict__ A, const float* __restrict__ R)
{
    const long i4 = ((long)blockIdx.x * 256 + threadIdx.x) << 2;
    const long off = i4 & 262143;
    const long bh = i4 >> 18;
    const int i = (int)(off >> 9);
    const int k = (int)(off & 511);
    const float ri = R[(bh << 9) + i];
    const float* Rk = R + (bh << 9) + k;
    float4 v = *(float4*)(A + i4);
    v.x = ri * Rk[0] * (v.x + ((k + 0) == i ? 1.0f : 0.0f));
    v.y = ri * Rk[1] * (v.y + ((k + 1) == i ? 1.0f : 0.0f));
    v.z = ri * Rk[2] * (v.z + ((k + 2) == i ? 1.0f : 0.0f));
    v.w = ri * Rk[3] * (v.w + ((k + 3) == i ? 1.0f : 0.0f));
    *(float4*)(A + i4) = v;
}

// ---------------------------------------------------------------------------
// Row softmax over 512, in place. Wave per row, 4 rows/block, no barriers.
// ---------------------------------------------------------------------------
__global__ __launch_bounds__(256)
void softmax_kernel(float* __restrict__ P)
{
    const int row = (blockIdx.x << 2) + (threadIdx.x >> 6);
    const int lane = threadIdx.x & 63;
    float* p = P + (long)row * 512 + (lane << 3);
    float4 v0 = *(float4*)p;
    float4 v1 = *(float4*)(p + 4);
    float mx = fmaxf(fmaxf(fmaxf(v0.x, v0.y), fmaxf(v0.z, v0.w)),
                     fmaxf(fmaxf(v1.x, v1.y), fmaxf(v1.z, v1.w)));
    #pragma unroll
    for (int off = 32; off; off >>= 1) mx = fmaxf(mx, __shfl_xor(mx, off, 64));
    float e[8];
    e[0] = __expf(v0.x - mx); e[1] = __expf(v0.y - mx);
    e[2] = __expf(v0.z - mx); e[3] = __expf(v0.w - mx);
    e[4] = __expf(v1.x - mx); e[5] = __expf(v1.y - mx);
    e[6] = __expf(v1.z - mx); e[7] = __expf(v1.w - mx);
    float s = (((e[0] + e[1]) + (e[2] + e[3])) + ((e[4] + e[5]) + (e[6] + e[7])));
    #pragma unroll
    for (int off = 32; off; off >>= 1) s += __shfl_xor(s, off, 64);
    const float inv = 1.0f / s;
    *(float4*)p       = make_float4(e[0] * inv, e[1] * inv, e[2] * inv, e[3] * inv);
    *(float4*)(p + 4) = make_float4(e[4] * inv, e[5] * inv, e[6] * inv, e[7] * inv);
}

// ---------------------------------------------------------------------------
// O = P @ V per head via split-bf16 MFMA, writing DIRECTLY to Of layout
// [B][L][H*HD]. M=512, N=64, K=512. 128x64 tile, 4 waves stacked on M.
// Grid (1, 4, 32).
// ---------------------------------------------------------------------------
__global__ __launch_bounds__(256)
void gemm_pv_mfma(const float* __restrict__ P, const float* __restrict__ V,
                  float* __restrict__ Of)
{
    const int bh = blockIdx.z;
    const float* __restrict__ Pp = P + (long)bh * 262144;
    const float* __restrict__ Vp = V + (long)bh * 32768;
    const int bb = bh >> 3, hh = bh & 7;
    const int m0 = blockIdx.y << 7;

    __shared__ short Ph[128 * 32], Pl[128 * 32], Vh[64 * 32], Vl[64 * 32];

    const int tid = threadIdx.x;
    const int lane = tid & 63, wv = tid >> 6;

    f32x4 acc[2][4] = {};

    for (int k0 = 0; k0 < 512; k0 += 32) {
        {
            const int row = tid >> 1;
            const int swz = (row & 3) ^ ((row >> 2) & 3);
            #pragma unroll
            for (int gg = 0; gg < 2; ++gg) {
                const int g = ((tid & 1) << 1) + gg;
                const float* src = Pp + (long)(m0 + row) * 512 + k0 + (g << 3);
                float v[8];
                *(float4*)&v[0] = *(const float4*)src;
                *(float4*)&v[4] = *(const float4*)(src + 4);
                unsigned hi[4], lo[4];
                split8(v, hi, lo);
                const int off = row * 32 + ((g ^ swz) << 3);
                *(uint4*)&Ph[off] = *(uint4*)hi;
                *(uint4*)&Pl[off] = *(uint4*)lo;
            }
        }
        {
            const int n = tid & 63, g = tid >> 6;
            const int swz = (n & 3) ^ ((n >> 2) & 3);
            float v[8];
            #pragma unroll
            for (int e = 0; e < 8; ++e)
                v[e] = Vp[(long)(k0 + (g << 3) + e) * 64 + n];
            unsigned hi[4], lo[4];
            split8(v, hi, lo);
            const int off = n * 32 + ((g ^ swz) << 3);
            *(uint4*)&Vh[off] = *(uint4*)hi;
            *(uint4*)&Vl[off] = *(uint4*)lo;
        }
        __syncthreads();

        {
            const int r = lane & 15, g = lane >> 4;
            const int lswz = (r & 3) ^ ((r >> 2) & 3);
            const int gslot = ((g ^ lswz) << 3);
            short8v afh[2], afl[2], bfh[4], bfl[4];
            #pragma unroll
            for (int fi = 0; fi < 2; ++fi) {
                const int abase = ((wv << 5) + (fi << 4) + r) * 32 + gslot;
                afh[fi] = *(short8v*)&Ph[abase];
                afl[fi] = *(short8v*)&Pl[abase];
            }
            #pragma unroll
            for (int fj = 0; fj < 4; ++fj) {
                const int bbase = ((fj << 4) + r) * 32 + gslot;
                bfh[fj] = *(short8v*)&Vh[bbase];
                bfl[fj] = *(short8v*)&Vl[bbase];
            }
            #pragma unroll
            for (int fi = 0; fi < 2; ++fi)
                #pragma unroll
                for (int fj = 0; fj < 4; ++fj) {
                    acc[fi][fj] = __builtin_amdgcn_mfma_f32_16x16x32_bf16(
                        afh[fi], bfh[fj], acc[fi][fj], 0, 0, 0);
                    acc[fi][fj] = __builtin_amdgcn_mfma_f32_16x16x32_bf16(
                        afh[fi], bfl[fj], acc[fi][fj], 0, 0, 0);
                    acc[fi][fj] = __builtin_amdgcn_mfma_f32_16x16x32_bf16(
                        afl[fi], bfh[fj], acc[fi][fj], 0, 0, 0);
                }
        }
        __syncthreads();
    }

    const int r = lane & 15, g = lane >> 4;
    #pragma unroll
    for (int fi = 0; fi < 2; ++fi) {
        const int l0 = m0 + (wv << 5) + fi * 16 + g * 4;
        #pragma unroll
        for (int fj = 0; fj < 4; ++fj) {
            const int d = fj * 16 + r;
            #pragma unroll
            for (int qq = 0; qq < 4; ++qq)
                Of[((long)((bb << 9) + l0 + qq) << 9) + (hh << 6) + d] = acc[fi][fj][qq];
        }
    }
}

// ---------------------------------------------------------------------------
extern "C" void kernel_launch(void* const* d_in, const int* in_sizes, int n_in,
                              void* d_out, int out_size, void* d_ws, size_t ws_size,
                              hipStream_t stream)
{
    const float* x  = (const float*)d_in[0];
    const float* Wq = (const float*)d_in[1];
    const float* Wk = (const float*)d_in[2];
    const float* Wv = (const float*)d_in[3];
    const float* Wo = (const float*)d_in[4];
    float* out = (float*)d_out;

    float* ws = (float*)d_ws;
    float* Q  = ws;                       // 1M floats (QKV base; later Of)
    float* Kt = Q  + (1u << 20);          // 1M
    float* V  = Kt + (1u << 20);          // 1M
    float* S  = V  + (1u << 20);          // 8M
    float* Am = S  + (8u << 20);          // 8M (adjacency -> A_hat)
    float* T  = Am + (8u << 20);          // 8M (A_hat@S temp)
    float* R  = T  + (8u << 20);          // 16K

    dim3 blk(256);

    // 1) fused QKV projections (split-bf16 MFMA)
    gemm_qkv_mfma<<<dim3(12, 16, 1), blk, 0, stream>>>(x, Wq, Wk, Wv, Q);

    // 2) S = Q K^T per head (MFMA, K=64)
    gemm_mfma<1><<<dim3(4, 4, 32), blk, 0, stream>>>(Q, Kt, S, 64, 64, 64, 512,
                                                     32768, 32768, 262144, 1.0f);

    // 3) adjacency (R5 skeleton, packed-fp16 inner loop)
    adj_kernel<<<dim3(36, 32), blk, 0, stream>>>(S, Am);

    // 4) row degrees -> R
    rowsum_kernel<<<dim3(4096), blk, 0, stream>>>(Am, R);

    // 5) A_hat in place
    ahat_kernel<<<dim3(8192), blk, 0, stream>>>(Am, R);

    // 6) T = A_hat @ S (MFMA)
    gemm_mfma<0><<<dim3(4, 4, 32), blk, 0, stream>>>(Am, S, T, 512, 512, 512, 512,
                                                     262144, 262144, 262144, 1.0f);

    // 7) J = T @ A_hat^T / 8 -> S (MFMA)
    gemm_mfma<1><<<dim3(4, 4, 32), blk, 0, stream>>>(T, Am, S, 512, 512, 512, 512,
                                                     262144, 262144, 262144, 0.125f);

    // 8) softmax rows of J (wave per row)
    softmax_kernel<<<dim3(4096), blk, 0, stream>>>(S);

    // 9) O = P @ V -> Of directly (reuse Q buffer)
    gemm_pv_mfma<<<dim3(1, 4, 32), blk, 0, stream>>>(S, V, Q);

    // 10) out = Of @ Wo (MFMA)
    gemm_mfma<0><<<dim3(4, 16, 1), blk, 0, stream>>>(Q, Wo, out, 512, 512, 512, 512,
                                                     0, 0, 0, 1.0f);
}

// Round 11
// 416.251 us; speedup vs baseline: 1.5925x; 1.0549x over previous
//
#include <hip/hip_runtime.h>
#include <math.h>

// Problem constants: B=4, H=8, L=512, HD=64, D=512, RHO=0.1
// Workspace (floats):
//   Q   : 1M   [BH][512][64]   (QKV base; later reused as Of [B][L][512])
//   Kt  : 1M
//   V   : 1M
//   S   : 8M   [BH][512][512]  (scores -> later J -> softmax'd P)
//   Am  : 8M   (adj partial 0 -> A_hat in place)
//   T   : 8M   (adj partial 1 -> A_hat@S temp)
//   R   : 16K  (row inv-sqrt degrees)

typedef __attribute__((ext_vector_type(8))) short short8v;
typedef __attribute__((ext_vector_type(4))) float f32x4;
typedef _Float16 h2 __attribute__((ext_vector_type(2)));

// ---------------------------------------------------------------------------
// bf16 split helper: pack 8 fp32 -> hi/lo bf16x8 (truncation split)
// ---------------------------------------------------------------------------
__device__ __forceinline__ void split8(const float* v, unsigned* hi, unsigned* lo)
{
    #pragma unroll
    for (int q = 0; q < 4; ++q) {
        const unsigned b0 = __float_as_uint(v[2 * q])     & 0xFFFF0000u;
        const unsigned b1 = __float_as_uint(v[2 * q + 1]) & 0xFFFF0000u;
        const float d0 = v[2 * q]     - __uint_as_float(b0);
        const float d1 = v[2 * q + 1] - __uint_as_float(b1);
        hi[q] = (b0 >> 16) | b1;
        lo[q] = (__float_as_uint(d0) >> 16) | (__float_as_uint(d1) & 0xFFFF0000u);
    }
}

// ---------------------------------------------------------------------------
// Split-bf16 MFMA GEMM. 128x128 tile, 256 threads (4 waves 2x2), K-step 32.
// BT=0: C = A @ B; BT=1: C = A @ B^T. acc = Ahi*Bhi + Ahi*Blo + Alo*Bhi.
// ---------------------------------------------------------------------------
template<int BT>
__global__ __launch_bounds__(256)
void gemm_mfma(const float* __restrict__ Ap, const float* __restrict__ Bp,
               float* __restrict__ Cp, int K, int lda, int ldb, int ldc,
               long sA, long sB, long sC, float scale)
{
    const float* __restrict__ A = Ap + (long)blockIdx.z * sA;
    const float* __restrict__ B = Bp + (long)blockIdx.z * sB;
    float* __restrict__ C = Cp + (long)blockIdx.z * sC;
    const int m0 = blockIdx.y << 7, n0 = blockIdx.x << 7;

    __shared__ short Ah[128 * 32], Al[128 * 32], Bh[128 * 32], Bl[128 * 32];

    const int tid = threadIdx.x;
    const int lane = tid & 63, wv = tid >> 6;
    const int wr = wv >> 1, wc = wv & 1;

    f32x4 acc[4][4] = {};

    for (int k0 = 0; k0 < K; k0 += 32) {
        {
            const int row = tid >> 1;
            const int swz = (row & 3) ^ ((row >> 2) & 3);
            #pragma unroll
            for (int gg = 0; gg < 2; ++gg) {
                const int g = ((tid & 1) << 1) + gg;
                const float* src = A + (long)(m0 + row) * lda + k0 + (g << 3);
                float v[8];
                *(float4*)&v[0] = *(const float4*)src;
                *(float4*)&v[4] = *(const float4*)(src + 4);
                unsigned hi[4], lo[4];
                split8(v, hi, lo);
                const int off = row * 32 + ((g ^ swz) << 3);
                *(uint4*)&Ah[off] = *(uint4*)hi;
                *(uint4*)&Al[off] = *(uint4*)lo;
            }
        }
        if (BT) {
            const int row = tid >> 1;
            const int swz = (row & 3) ^ ((row >> 2) & 3);
            #pragma unroll
            for (int gg = 0; gg < 2; ++gg) {
                const int g = ((tid & 1) << 1) + gg;
                const float* src = B + (long)(n0 + row) * ldb + k0 + (g << 3);
                float v[8];
                *(float4*)&v[0] = *(const float4*)src;
                *(float4*)&v[4] = *(const float4*)(src + 4);
                unsigned hi[4], lo[4];
                split8(v, hi, lo);
                const int off = row * 32 + ((g ^ swz) << 3);
                *(uint4*)&Bh[off] = *(uint4*)hi;
                *(uint4*)&Bl[off] = *(uint4*)lo;
            }
        } else {
            const int n = tid & 127;
            const int swz = (n & 3) ^ ((n >> 2) & 3);
            #pragma unroll
            for (int gg = 0; gg < 2; ++gg) {
                const int g = ((tid >> 7) << 1) + gg;
                float v[8];
                #pragma unroll
                for (int e = 0; e < 8; ++e)
                    v[e] = B[(long)(k0 + (g << 3) + e) * ldb + n0 + n];
                unsigned hi[4], lo[4];
                split8(v, hi, lo);
                const int off = n * 32 + ((g ^ swz) << 3);
                *(uint4*)&Bh[off] = *(uint4*)hi;
                *(uint4*)&Bl[off] = *(uint4*)lo;
            }
        }
        __syncthreads();

        {
            const int r = lane & 15, g = lane >> 4;
            const int lswz = (r & 3) ^ ((r >> 2) & 3);
            const int gslot = ((g ^ lswz) << 3);
            const int abase = ((wr << 6) + r) * 32 + gslot;
            const int bbase = ((wc << 6) + r) * 32 + gslot;
            short8v afh[4], afl[4], bfh[4], bfl[4];
            #pragma unroll
            for (int f = 0; f < 4; ++f) {
                afh[f] = *(short8v*)&Ah[abase + f * 512];
                afl[f] = *(short8v*)&Al[abase + f * 512];
                bfh[f] = *(short8v*)&Bh[bbase + f * 512];
                bfl[f] = *(short8v*)&Bl[bbase + f * 512];
            }
            #pragma unroll
            for (int fi = 0; fi < 4; ++fi)
                #pragma unroll
                for (int fj = 0; fj < 4; ++fj) {
                    acc[fi][fj] = __builtin_amdgcn_mfma_f32_16x16x32_bf16(
                        afh[fi], bfh[fj], acc[fi][fj], 0, 0, 0);
                    acc[fi][fj] = __builtin_amdgcn_mfma_f32_16x16x32_bf16(
                        afh[fi], bfl[fj], acc[fi][fj], 0, 0, 0);
                    acc[fi][fj] = __builtin_amdgcn_mfma_f32_16x16x32_bf16(
                        afl[fi], bfh[fj], acc[fi][fj], 0, 0, 0);
                }
        }
        __syncthreads();
    }

    // C/D layout: col = lane&15, row = (lane>>4)*4 + reg  [m89/m91]
    const int r = lane & 15, g = lane >> 4;
    #pragma unroll
    for (int fi = 0; fi < 4; ++fi) {
        const int gr0 = m0 + (wr << 6) + fi * 16 + g * 4;
        #pragma unroll
        for (int fj = 0; fj < 4; ++fj) {
            const int gc = n0 + (wc << 6) + fj * 16 + r;
            #pragma unroll
            for (int qq = 0; qq < 4; ++qq)
                C[(long)(gr0 + qq) * ldc + gc] = acc[fi][fj][qq] * scale;
        }
    }
}

// ---------------------------------------------------------------------------
// Fused QKV projection via split-bf16 MFMA: x[2048x512] @ {Wq|Wk|Wv}[512x512]
// -> QKV [3][BH][512][64]. Grid (12, 16).
// ---------------------------------------------------------------------------
__global__ __launch_bounds__(256)
void gemm_qkv_mfma(const float* __restrict__ x, const float* __restrict__ Wq,
                   const float* __restrict__ Wk, const float* __restrict__ Wv,
                   float* __restrict__ QKV)
{
    const int m0 = blockIdx.y << 7;
    const int ng = blockIdx.x << 7;
    const float* __restrict__ W = (ng < 512) ? Wq : (ng < 1024) ? Wk : Wv;
    const int n0 = ng & 511;
    float* __restrict__ C = QKV + (long)(ng >> 9) * (1 << 20);

    __shared__ short Ah[128 * 32], Al[128 * 32], Bh[128 * 32], Bl[128 * 32];

    const int tid = threadIdx.x;
    const int lane = tid & 63, wv = tid >> 6;
    const int wr = wv >> 1, wc = wv & 1;

    f32x4 acc[4][4] = {};

    for (int k0 = 0; k0 < 512; k0 += 32) {
        {
            const int row = tid >> 1;
            const int swz = (row & 3) ^ ((row >> 2) & 3);
            #pragma unroll
            for (int gg = 0; gg < 2; ++gg) {
                const int g = ((tid & 1) << 1) + gg;
                const float* src = x + (long)(m0 + row) * 512 + k0 + (g << 3);
                float v[8];
                *(float4*)&v[0] = *(const float4*)src;
                *(float4*)&v[4] = *(const float4*)(src + 4);
                unsigned hi[4], lo[4];
                split8(v, hi, lo);
                const int off = row * 32 + ((g ^ swz) << 3);
                *(uint4*)&Ah[off] = *(uint4*)hi;
                *(uint4*)&Al[off] = *(uint4*)lo;
            }
        }
        {
            const int n = tid & 127;
            const int swz = (n & 3) ^ ((n >> 2) & 3);
            #pragma unroll
            for (int gg = 0; gg < 2; ++gg) {
                const int g = ((tid >> 7) << 1) + gg;
                float v[8];
                #pragma unroll
                for (int e = 0; e < 8; ++e)
                    v[e] = W[(long)(k0 + (g << 3) + e) * 512 + n0 + n];
                unsigned hi[4], lo[4];
                split8(v, hi, lo);
                const int off = n * 32 + ((g ^ swz) << 3);
                *(uint4*)&Bh[off] = *(uint4*)hi;
                *(uint4*)&Bl[off] = *(uint4*)lo;
            }
        }
        __syncthreads();

        {
            const int r = lane & 15, g = lane >> 4;
            const int lswz = (r & 3) ^ ((r >> 2) & 3);
            const int gslot = ((g ^ lswz) << 3);
            const int abase = ((wr << 6) + r) * 32 + gslot;
            const int bbase = ((wc << 6) + r) * 32 + gslot;
            short8v afh[4], afl[4], bfh[4], bfl[4];
            #pragma unroll
            for (int f = 0; f < 4; ++f) {
                afh[f] = *(short8v*)&Ah[abase + f * 512];
                afl[f] = *(short8v*)&Al[abase + f * 512];
                bfh[f] = *(short8v*)&Bh[bbase + f * 512];
                bfl[f] = *(short8v*)&Bl[bbase + f * 512];
            }
            #pragma unroll
            for (int fi = 0; fi < 4; ++fi)
                #pragma unroll
                for (int fj = 0; fj < 4; ++fj) {
                    acc[fi][fj] = __builtin_amdgcn_mfma_f32_16x16x32_bf16(
                        afh[fi], bfh[fj], acc[fi][fj], 0, 0, 0);
                    acc[fi][fj] = __builtin_amdgcn_mfma_f32_16x16x32_bf16(
                        afh[fi], bfl[fj], acc[fi][fj], 0, 0, 0);
                    acc[fi][fj] = __builtin_amdgcn_mfma_f32_16x16x32_bf16(
                        afl[fi], bfh[fj], acc[fi][fj], 0, 0, 0);
                }
        }
        __syncthreads();
    }

    const int r = lane & 15, g = lane >> 4;
    #pragma unroll
    for (int fi = 0; fi < 4; ++fi) {
        const int gr0 = m0 + (wr << 6) + fi * 16 + g * 4;
        #pragma unroll
        for (int fj = 0; fj < 4; ++fj) {
            const int nl = n0 + (wc << 6) + fj * 16 + r;
            const int h = nl >> 6, d = nl & 63;
            #pragma unroll
            for (int qq = 0; qq < 4; ++qq) {
                const int m = gr0 + qq;
                const int b = m >> 9, l = m & 511;
                C[((long)((b * 8 + h) * 512 + l)) * 64 + d] = acc[fi][fj][qq];
            }
        }
    }
}

// ---------------------------------------------------------------------------
// Adjacency v9: packed-fp16 inner loop + register prefetch + j-split x2.
//   Partial[i,k] = 2^-15 * sum_{j in half} u·[u > 6.4], u = S_ij*S_kj, diag 0.
// Per j-PAIR (h2): d = a*b - 6.4; t = max(d,0);
//   m = min(t*32768 + t, t + 6.4)      // = (t>0) ? t+6.4 : 0
//   acc += m                           // 6 packed ops / 2 products
// Pipeline per 16-j chunk: cvt+ds_write(c) -> issue global loads(c+1) ->
//   lgkmcnt(0)-only drain (loads stay in flight) -> compute(c).
// VGPR: acc2 64 + prefetch 32 + addr ~ 110, capped <128 by launch_bounds(256,4).
// Grid (36 upper-tri tile pairs, 2 j-halves, 32 bh). Mirror write (symmetry).
// Partials combined in rowsum/ahat (pow2 scale commutes -> bit-identical).
// ---------------------------------------------------------------------------
__global__ __launch_bounds__(256, 4)
void adj_kernel(const float* __restrict__ S, float* __restrict__ P0,
                float* __restrict__ P1)
{
    const int bh = blockIdx.z;
    const float* __restrict__ Sh = S + (long)bh * 262144;
    float* __restrict__ Ph = ((blockIdx.y == 0) ? P0 : P1) + (long)bh * 262144;
    const int jbase = blockIdx.y << 8;

    int ti = 0, rem = blockIdx.x;
    while (rem >= 8 - ti) { rem -= 8 - ti; ++ti; }
    const int tk = ti + rem;
    const int i0 = ti << 6, k0 = tk << 6;

    __shared__ __align__(16) char smem_raw[17408];   // 4 waves x 2 sides x [8][68] h2

    const int tid  = threadIdx.x;
    const int lane = tid & 63;
    const int wv   = tid >> 6;
    const int ly8  = (lane >> 3) << 3;
    const int lx8  = (lane & 7) << 3;
    const int r4   = lane >> 2;          // 0..15 row group
    const int q    = lane & 3;           // 0..3 j-quad

    h2 (*stgL)[68] = (h2(*)[68])(smem_raw + wv * 4352);
    h2 (*stgR)[68] = (h2(*)[68])(smem_raw + wv * 4352 + 2176);

    const h2 nC2  = { (_Float16)(-6.4f), (_Float16)(-6.4f) };
    const h2 z2   = { (_Float16)0.0f,    (_Float16)0.0f };
    const h2 big2 = { (_Float16)32768.0f,(_Float16)32768.0f };
    const h2 c2   = { (_Float16)6.4f,    (_Float16)6.4f };

    h2 acc2[8][8];
    #pragma unroll
    for (int i = 0; i < 8; ++i)
        #pragma unroll
        for (int j = 0; j < 8; ++j)
            acc2[i][j] = z2;

    const int jw = jbase + (wv << 6);    // this wave's 64-j range
    const float* srcL = Sh + (long)(i0 + r4) * 512 + jw + (q << 2);
    const float* srcR = Sh + (long)(k0 + r4) * 512 + jw + (q << 2);

    float4 rl[4], rr[4];
    // prologue: chunk 0 loads
    #pragma unroll
    for (int p = 0; p < 4; ++p) {
        rl[p] = *(const float4*)(srcL + (long)(p << 4) * 512);
        rr[p] = *(const float4*)(srcR + (long)(p << 4) * 512);
    }

    for (int c = 0; c < 4; ++c) {
        // cvt + ds_write chunk c from regs
        #pragma unroll
        for (int p = 0; p < 4; ++p) {
            const int row = r4 + (p << 4);
            h2 h0, h1;
            h0[0] = (_Float16)rl[p].x; h0[1] = (_Float16)rl[p].y;
            h1[0] = (_Float16)rl[p].z; h1[1] = (_Float16)rl[p].w;
            stgL[(q << 1) + 0][row] = h0;
            stgL[(q << 1) + 1][row] = h1;
            h0[0] = (_Float16)rr[p].x; h0[1] = (_Float16)rr[p].y;
            h1[0] = (_Float16)rr[p].z; h1[1] = (_Float16)rr[p].w;
            stgR[(q << 1) + 0][row] = h0;
            stgR[(q << 1) + 1][row] = h1;
        }
        // issue next chunk's global loads (land under compute below)
        if (c < 3) {
            const int joff = (c + 1) << 4;
            #pragma unroll
            for (int p = 0; p < 4; ++p) {
                rl[p] = *(const float4*)(srcL + (long)(p << 4) * 512 + joff);
                rr[p] = *(const float4*)(srcR + (long)(p << 4) * 512 + joff);
            }
        }
        // LDS-only drain: prefetch loads stay in flight
        asm volatile("s_waitcnt lgkmcnt(0)" ::: "memory");
        __builtin_amdgcn_sched_barrier(0);
        #pragma unroll
        for (int jp = 0; jp < 8; ++jp) {
            h2 a2[8], b2[8];
            *(uint4*)&a2[0] = *(const uint4*)&stgL[jp][ly8];
            *(uint4*)&a2[4] = *(const uint4*)&stgL[jp][ly8 + 4];
            *(uint4*)&b2[0] = *(const uint4*)&stgR[jp][lx8];
            *(uint4*)&b2[4] = *(const uint4*)&stgR[jp][lx8 + 4];
            #pragma unroll
            for (int i = 0; i < 8; ++i)
                #pragma unroll
                for (int j = 0; j < 8; ++j) {
                    const h2 d = a2[i] * b2[j] + nC2;
                    const h2 t = __builtin_elementwise_max(d, z2);
                    const h2 m = __builtin_elementwise_min(t * big2 + t, t + c2);
                    acc2[i][j] += m;
                }
        }
    }

    // ---- quarter-wise fp32 reduce: (w0+w1)+(w3+w2) -> wave 0 ----
    float* buf0 = (float*)smem_raw;                   // 64 x 17 floats
    float* buf1 = (float*)(smem_raw + 4352);
    float  f[8][8];                                   // wv0's final totals

    #pragma unroll
    for (int qp = 0; qp < 4; ++qp) {
        float v[16];
        #pragma unroll
        for (int e = 0; e < 16; ++e) {
            const h2 hh = acc2[(qp << 1) + (e >> 3)][e & 7];
            v[e] = (float)hh[0] + (float)hh[1];
        }
        __syncthreads();
        if (wv == 1 || wv == 2) {
            float* dst = (wv == 1 ? buf0 : buf1) + lane * 17;
            #pragma unroll
            for (int e = 0; e < 16; ++e) dst[e] = v[e];
        }
        __syncthreads();
        if (wv == 0 || wv == 3) {
            const float* src = (wv == 0 ? buf0 : buf1) + lane * 17;
            #pragma unroll
            for (int e = 0; e < 16; ++e) v[e] += src[e];
        }
        __syncthreads();
        if (wv == 3) {
            float* dst = buf0 + lane * 17;
            #pragma unroll
            for (int e = 0; e < 16; ++e) dst[e] = v[e];
        }
        __syncthreads();
        if (wv == 0) {
            const float* src = buf0 + lane * 17;
            #pragma unroll
            for (int e = 0; e < 16; ++e)
                f[(qp << 1) + (e >> 3)][e & 7] = v[e] + src[e];
        }
    }

    if (wv == 0) {
        const float SC = 1.0f / 32768.0f;    // 2^-15 = (1/64)*(1/512), exact
        #pragma unroll
        for (int i = 0; i < 8; ++i)
            #pragma unroll
            for (int j = 0; j < 8; ++j)
                f[i][j] *= SC;
        if (ti == tk) {
            #pragma unroll
            for (int i = 0; i < 8; ++i)
                #pragma unroll
                for (int j = 0; j < 8; ++j)
                    if (ly8 + i == lx8 + j) f[i][j] = 0.0f;
        }
        #pragma unroll
        for (int i = 0; i < 8; ++i) {
            float* dst = Ph + (long)(i0 + ly8 + i) * 512 + k0 + lx8;
            *(float4*)dst       = make_float4(f[i][0], f[i][1], f[i][2], f[i][3]);
            *(float4*)(dst + 4) = make_float4(f[i][4], f[i][5], f[i][6], f[i][7]);
        }
        if (ti != tk) {
            #pragma unroll
            for (int j = 0; j < 8; ++j) {
                float* dst = Ph + (long)(k0 + lx8 + j) * 512 + i0 + ly8;
                *(float4*)dst       = make_float4(f[0][j], f[1][j], f[2][j], f[3][j]);
                *(float4*)(dst + 4) = make_float4(f[4][j], f[5][j], f[6][j], f[7][j]);
            }
        }
    }
}

// ---------------------------------------------------------------------------
// Row degree from partials: R[row] = 1/sqrt(clip(1 + sum(P0+P1), 1e-6))
// ---------------------------------------------------------------------------
__global__ __launch_bounds__(256)
void rowsum_kernel(const float* __restrict__ P0, const float* __restrict__ P1,
                   float* __restrict__ R)
{
    const int row = (blockIdx.x << 2) + (threadIdx.x >> 6);
    const int lane = threadIdx.x & 63;
    const float* p0 = P0 + (long)row * 512;
    const float* p1 = P1 + (long)row * 512;
    float s = 0.0f;
    #pragma unroll
    for (int t = 0; t < 8; ++t) s += p0[lane + (t << 6)] + p1[lane + (t << 6)];
    #pragma unroll
    for (int off = 32; off; off >>= 1) s += __shfl_xor(s, off, 64);
    if (lane == 0) R[row] = 1.0f / sqrtf(fmaxf(1.0f + s, 1e-6f));
}

// ---------------------------------------------------------------------------
// A_hat[i,k] = R[i]*R[k]*((P0+P1) + (i==k)) -> written to P0
// ---------------------------------------------------------------------------
__global__ __launch_bounds__(256)
void ahat_kernel(float* __restrict__ P0, const float* __restrict__ P1,
                 const float* __restrict__ R)
{
    const long i4 = ((long)blockIdx.x * 256 + threadIdx.x) << 2;
    const long off = i4 & 262143;
    const long bh = i4 >> 18;
    const int i = (int)(off >> 9);
    const int k = (int)(off & 511);
    const float ri = R[(bh << 9) + i];
    const float* Rk = R + (bh << 9) + k;
    float4 v0 = *(float4*)(P0 + i4);
    float4 v1 = *(const float4*)(P1 + i4);
    v0.x = ri * Rk[0] * ((v0.x + v1.x) + ((k + 0) == i ? 1.0f : 0.0f));
    v0.y = ri * Rk[1] * ((v0.y + v1.y) + ((k + 1) == i ? 1.0f : 0.0f));
    v0.z = ri * Rk[2] * ((v0.z + v1.z) + ((k + 2) == i ? 1.0f : 0.0f));
    v0.w = ri * Rk[3] * ((v0.w + v1.w) + ((k + 3) == i ? 1.0f : 0.0f));
    *(float4*)(P0 + i4) = v0;
}

// ---------------------------------------------------------------------------
// Row softmax over 512, in place. Wave per row, 4 rows/block, no barriers.
// ---------------------------------------------------------------------------
__global__ __launch_bounds__(256)
void softmax_kernel(float* __restrict__ P)
{
    const int row = (blockIdx.x << 2) + (threadIdx.x >> 6);
    const int lane = threadIdx.x & 63;
    float* p = P + (long)row * 512 + (lane << 3);
    float4 v0 = *(float4*)p;
    float4 v1 = *(float4*)(p + 4);
    float mx = fmaxf(fmaxf(fmaxf(v0.x, v0.y), fmaxf(v0.z, v0.w)),
                     fmaxf(fmaxf(v1.x, v1.y), fmaxf(v1.z, v1.w)));
    #pragma unroll
    for (int off = 32; off; off >>= 1) mx = fmaxf(mx, __shfl_xor(mx, off, 64));
    float e[8];
    e[0] = __expf(v0.x - mx); e[1] = __expf(v0.y - mx);
    e[2] = __expf(v0.z - mx); e[3] = __expf(v0.w - mx);
    e[4] = __expf(v1.x - mx); e[5] = __expf(v1.y - mx);
    e[6] = __expf(v1.z - mx); e[7] = __expf(v1.w - mx);
    float s = (((e[0] + e[1]) + (e[2] + e[3])) + ((e[4] + e[5]) + (e[6] + e[7])));
    #pragma unroll
    for (int off = 32; off; off >>= 1) s += __shfl_xor(s, off, 64);
    const float inv = 1.0f / s;
    *(float4*)p       = make_float4(e[0] * inv, e[1] * inv, e[2] * inv, e[3] * inv);
    *(float4*)(p + 4) = make_float4(e[4] * inv, e[5] * inv, e[6] * inv, e[7] * inv);
}

// ---------------------------------------------------------------------------
// O = P @ V per head via split-bf16 MFMA, writing DIRECTLY to Of layout
// [B][L][H*HD]. M=512, N=64, K=512. 128x64 tile, 4 waves stacked on M.
// Grid (1, 4, 32).
// ---------------------------------------------------------------------------
__global__ __launch_bounds__(256)
void gemm_pv_mfma(const float* __restrict__ P, const float* __restrict__ V,
                  float* __restrict__ Of)
{
    const int bh = blockIdx.z;
    const float* __restrict__ Pp = P + (long)bh * 262144;
    const float* __restrict__ Vp = V + (long)bh * 32768;
    const int bb = bh >> 3, hh = bh & 7;
    const int m0 = blockIdx.y << 7;

    __shared__ short Ph[128 * 32], Pl[128 * 32], Vh[64 * 32], Vl[64 * 32];

    const int tid = threadIdx.x;
    const int lane = tid & 63, wv = tid >> 6;

    f32x4 acc[2][4] = {};

    for (int k0 = 0; k0 < 512; k0 += 32) {
        {
            const int row = tid >> 1;
            const int swz = (row & 3) ^ ((row >> 2) & 3);
            #pragma unroll
            for (int gg = 0; gg < 2; ++gg) {
                const int g = ((tid & 1) << 1) + gg;
                const float* src = Pp + (long)(m0 + row) * 512 + k0 + (g << 3);
                float v[8];
                *(float4*)&v[0] = *(const float4*)src;
                *(float4*)&v[4] = *(const float4*)(src + 4);
                unsigned hi[4], lo[4];
                split8(v, hi, lo);
                const int off = row * 32 + ((g ^ swz) << 3);
                *(uint4*)&Ph[off] = *(uint4*)hi;
                *(uint4*)&Pl[off] = *(uint4*)lo;
            }
        }
        {
            const int n = tid & 63, g = tid >> 6;
            const int swz = (n & 3) ^ ((n >> 2) & 3);
            float v[8];
            #pragma unroll
            for (int e = 0; e < 8; ++e)
                v[e] = Vp[(long)(k0 + (g << 3) + e) * 64 + n];
            unsigned hi[4], lo[4];
            split8(v, hi, lo);
            const int off = n * 32 + ((g ^ swz) << 3);
            *(uint4*)&Vh[off] = *(uint4*)hi;
            *(uint4*)&Vl[off] = *(uint4*)lo;
        }
        __syncthreads();

        {
            const int r = lane & 15, g = lane >> 4;
            const int lswz = (r & 3) ^ ((r >> 2) & 3);
            const int gslot = ((g ^ lswz) << 3);
            short8v afh[2], afl[2], bfh[4], bfl[4];
            #pragma unroll
            for (int fi = 0; fi < 2; ++fi) {
                const int abase = ((wv << 5) + (fi << 4) + r) * 32 + gslot;
                afh[fi] = *(short8v*)&Ph[abase];
                afl[fi] = *(short8v*)&Pl[abase];
            }
            #pragma unroll
            for (int fj = 0; fj < 4; ++fj) {
                const int bbase = ((fj << 4) + r) * 32 + gslot;
                bfh[fj] = *(short8v*)&Vh[bbase];
                bfl[fj] = *(short8v*)&Vl[bbase];
            }
            #pragma unroll
            for (int fi = 0; fi < 2; ++fi)
                #pragma unroll
                for (int fj = 0; fj < 4; ++fj) {
                    acc[fi][fj] = __builtin_amdgcn_mfma_f32_16x16x32_bf16(
                        afh[fi], bfh[fj], acc[fi][fj], 0, 0, 0);
                    acc[fi][fj] = __builtin_amdgcn_mfma_f32_16x16x32_bf16(
                        afh[fi], bfl[fj], acc[fi][fj], 0, 0, 0);
                    acc[fi][fj] = __builtin_amdgcn_mfma_f32_16x16x32_bf16(
                        afl[fi], bfh[fj], acc[fi][fj], 0, 0, 0);
                }
        }
        __syncthreads();
    }

    const int r = lane & 15, g = lane >> 4;
    #pragma unroll
    for (int fi = 0; fi < 2; ++fi) {
        const int l0 = m0 + (wv << 5) + fi * 16 + g * 4;
        #pragma unroll
        for (int fj = 0; fj < 4; ++fj) {
            const int d = fj * 16 + r;
            #pragma unroll
            for (int qq = 0; qq < 4; ++qq)
                Of[((long)((bb << 9) + l0 + qq) << 9) + (hh << 6) + d] = acc[fi][fj][qq];
        }
    }
}

// ---------------------------------------------------------------------------
extern "C" void kernel_launch(void* const* d_in, const int* in_sizes, int n_in,
                              void* d_out, int out_size, void* d_ws, size_t ws_size,
                              hipStream_t stream)
{
    const float* x  = (const float*)d_in[0];
    const float* Wq = (const float*)d_in[1];
    const float* Wk = (const float*)d_in[2];
    const float* Wv = (const float*)d_in[3];
    const float* Wo = (const float*)d_in[4];
    float* out = (float*)d_out;

    float* ws = (float*)d_ws;
    float* Q  = ws;                       // 1M floats (QKV base; later Of)
    float* Kt = Q  + (1u << 20);          // 1M
    float* V  = Kt + (1u << 20);          // 1M
    float* S  = V  + (1u << 20);          // 8M
    float* Am = S  + (8u << 20);          // 8M (adj partial 0 -> A_hat)
    float* T  = Am + (8u << 20);          // 8M (adj partial 1 -> A_hat@S temp)
    float* R  = T  + (8u << 20);          // 16K

    dim3 blk(256);

    // 1) fused QKV projections (split-bf16 MFMA)
    gemm_qkv_mfma<<<dim3(12, 16, 1), blk, 0, stream>>>(x, Wq, Wk, Wv, Q);

    // 2) S = Q K^T per head (MFMA, K=64)
    gemm_mfma<1><<<dim3(4, 4, 32), blk, 0, stream>>>(Q, Kt, S, 64, 64, 64, 512,
                                                     32768, 32768, 262144, 1.0f);

    // 3) adjacency partials (fp16 packed, prefetch, j-split x2)
    adj_kernel<<<dim3(36, 2, 32), blk, 0, stream>>>(S, Am, T);

    // 4) row degrees -> R (combines partials)
    rowsum_kernel<<<dim3(4096), blk, 0, stream>>>(Am, T, R);

    // 5) A_hat (combines partials) -> Am
    ahat_kernel<<<dim3(8192), blk, 0, stream>>>(Am, T, R);

    // 6) T = A_hat @ S (MFMA)
    gemm_mfma<0><<<dim3(4, 4, 32), blk, 0, stream>>>(Am, S, T, 512, 512, 512, 512,
                                                     262144, 262144, 262144, 1.0f);

    // 7) J = T @ A_hat^T / 8 -> S (MFMA)
    gemm_mfma<1><<<dim3(4, 4, 32), blk, 0, stream>>>(T, Am, S, 512, 512, 512, 512,
                                                     262144, 262144, 262144, 0.125f);

    // 8) softmax rows of J (wave per row)
    softmax_kernel<<<dim3(4096), blk, 0, stream>>>(S);

    // 9) O = P @ V -> Of directly (reuse Q buffer)
    gemm_pv_mfma<<<dim3(1, 4, 32), blk, 0, stream>>>(S, V, Q);

    // 10) out = Of @ Wo (MFMA)
    gemm_mfma<0><<<dim3(4, 16, 1), blk, 0, stream>>>(Q, Wo, out, 512, 512, 512, 512,
                                                     0, 0, 0, 1.0f);
}